// Round 1
// baseline (4692.835 us; speedup 1.0000x reference)
//
#include <hip/hip_runtime.h>
#include <hip/hip_bf16.h>
#include <math.h>

#define B_   4
#define S_   512
#define D_   4096
#define H_   32
#define G_   8
#define HD_  128
#define REP_ 4
#define KV_  (G_ * HD_)   // 1024

// ---------------- GEMM: C[M,N] = A[M,K] @ W[K,N] + bias ----------------
// BM=BN=64, BK=16, 256 threads, 4x4 micro-tile per thread. fp32 vector ALU.
__global__ __launch_bounds__(256) void gemm_bias_kernel(
    const float* __restrict__ A, const float* __restrict__ W,
    const float* __restrict__ bias, float* __restrict__ C,
    int M, int N, int K)
{
    __shared__ float sA[16][68];   // [k][m], padded to 68 (keeps 16B align, 2-way banks)
    __shared__ float sB[16][68];   // [k][n]

    const int tid = threadIdx.x;
    const int tx = tid & 15, ty = tid >> 4;
    const int m0 = blockIdx.y * 64, n0 = blockIdx.x * 64;

    // A tile load mapping: 64 rows x 16 k, one float4 per thread
    const int rowA  = tid >> 2;
    const int colA4 = (tid & 3) * 4;
    // B tile load mapping: 16 k-rows x 64 n, one float4 per thread
    const int rowB  = tid >> 4;
    const int colB4 = (tid & 15) * 4;

    float acc[4][4] = {};

    for (int k0 = 0; k0 < K; k0 += 16) {
        const float4 av = *reinterpret_cast<const float4*>(
            &A[(size_t)(m0 + rowA) * K + k0 + colA4]);
        const float4 bv = *reinterpret_cast<const float4*>(
            &W[(size_t)(k0 + rowB) * N + n0 + colB4]);
        __syncthreads();   // previous iter's compute done before overwrite
        sA[colA4 + 0][rowA] = av.x;
        sA[colA4 + 1][rowA] = av.y;
        sA[colA4 + 2][rowA] = av.z;
        sA[colA4 + 3][rowA] = av.w;
        *reinterpret_cast<float4*>(&sB[rowB][colB4]) = bv;
        __syncthreads();
        #pragma unroll
        for (int kk = 0; kk < 16; ++kk) {
            const float4 a4 = *reinterpret_cast<const float4*>(&sA[kk][ty * 4]);
            const float4 b4 = *reinterpret_cast<const float4*>(&sB[kk][tx * 4]);
            const float ar[4] = {a4.x, a4.y, a4.z, a4.w};
            const float br[4] = {b4.x, b4.y, b4.z, b4.w};
            #pragma unroll
            for (int i = 0; i < 4; ++i)
                #pragma unroll
                for (int j = 0; j < 4; ++j)
                    acc[i][j] += ar[i] * br[j];
        }
    }

    #pragma unroll
    for (int i = 0; i < 4; ++i) {
        const int m = m0 + ty * 4 + i;
        const int n = n0 + tx * 4;
        float4 o;
        o.x = acc[i][0] + bias[n + 0];
        o.y = acc[i][1] + bias[n + 1];
        o.z = acc[i][2] + bias[n + 2];
        o.w = acc[i][3] + bias[n + 3];
        *reinterpret_cast<float4*>(&C[(size_t)m * N + n]) = o;
    }
}

// ---------------- RoPE (in-place), optional extra scale -----------------
// buf: (B*S tokens, nh heads, HD). Pair (j, j+64) rotated by angle s*inv_freq[j].
__global__ void rope_kernel(float* __restrict__ buf, int nh, float scale)
{
    const int i = blockIdx.x * blockDim.x + threadIdx.x;
    const int total = B_ * S_ * nh * 64;
    if (i >= total) return;
    const int j     = i & 63;
    const int t2    = i >> 6;
    const int head  = t2 % nh;
    const int token = t2 / nh;
    const int s     = token % S_;

    const size_t base = ((size_t)token * nh + head) * HD_;
    // inv_freq = 10000^(-2j/HD)
    const float inv = __expf(-9.210340371976184f * (2.f * j) / (float)HD_);
    const float ang = (float)s * inv;
    float sn, cs;
    __sincosf(ang, &sn, &cs);
    const float x1 = buf[base + j];
    const float x2 = buf[base + j + 64];
    buf[base + j]      = (x1 * cs - x2 * sn) * scale;
    buf[base + j + 64] = (x2 * cs + x1 * sn) * scale;
}

// ---------------- Attention: one block per (b, h, q-row) ----------------
// q (already rope'd and scaled by 1/HD) is overwritten in place with the
// attention output row — each block owns exactly its own row.
__global__ __launch_bounds__(128) void attn_kernel(
    const float* __restrict__ k, const float* __restrict__ v,
    float* __restrict__ q)
{
    const int qpos = blockIdx.x, h = blockIdx.y, b = blockIdx.z;
    const int g = h >> 2;               // h / REP
    const int tid = threadIdx.x;

    __shared__ float qs[HD_];
    __shared__ float ls[S_];
    __shared__ float red[2];

    float* qrow = q + (size_t)(b * S_ + qpos) * D_ + h * HD_;
    qs[tid] = qrow[tid];
    __syncthreads();

    // logits
    const float* kb = k + (size_t)b * S_ * KV_ + g * HD_;
    for (int kp = tid; kp < S_; kp += 128) {
        const float4* kr = reinterpret_cast<const float4*>(kb + (size_t)kp * KV_);
        float dot = 0.f;
        #pragma unroll
        for (int d4 = 0; d4 < 32; ++d4) {
            const float4 kv4 = kr[d4];
            const float4 qv  = *reinterpret_cast<const float4*>(&qs[d4 * 4]);
            dot += qv.x * kv4.x + qv.y * kv4.y + qv.z * kv4.z + qv.w * kv4.w;
        }
        ls[kp] = dot;
    }
    __syncthreads();

    // max-reduce
    float m = -1e30f;
    for (int kp = tid; kp < S_; kp += 128) m = fmaxf(m, ls[kp]);
    #pragma unroll
    for (int off = 32; off >= 1; off >>= 1) m = fmaxf(m, __shfl_down(m, off));
    if ((tid & 63) == 0) red[tid >> 6] = m;
    __syncthreads();
    m = fmaxf(red[0], red[1]);

    // exp + sum-reduce
    float ssum = 0.f;
    for (int kp = tid; kp < S_; kp += 128) {
        const float p = __expf(ls[kp] - m);
        ls[kp] = p;
        ssum += p;
    }
    #pragma unroll
    for (int off = 32; off >= 1; off >>= 1) ssum += __shfl_down(ssum, off);
    __syncthreads();                    // everyone done reading red (max)
    if ((tid & 63) == 0) red[tid >> 6] = ssum;
    __syncthreads();                    // also guarantees ls (p) is visible
    const float inv = 1.f / (red[0] + red[1]);

    // PV: thread tid owns output dim d = tid; coalesced V reads
    const float* vb = v + (size_t)b * S_ * KV_ + g * HD_ + tid;
    float acc = 0.f;
    for (int kp = 0; kp < S_; ++kp)
        acc += ls[kp] * vb[(size_t)kp * KV_];
    qrow[tid] = acc * inv;
}

extern "C" void kernel_launch(void* const* d_in, const int* in_sizes, int n_in,
                              void* d_out, int out_size, void* d_ws, size_t ws_size,
                              hipStream_t stream)
{
    const float* x  = (const float*)d_in[0];
    const float* wq = (const float*)d_in[1];
    const float* bq = (const float*)d_in[2];
    const float* wk = (const float*)d_in[3];
    const float* bk = (const float*)d_in[4];
    const float* wv = (const float*)d_in[5];
    const float* bv = (const float*)d_in[6];
    const float* wo = (const float*)d_in[7];
    const float* bo = (const float*)d_in[8];
    float* out = (float*)d_out;

    float* q    = (float*)d_ws;                       // B*S*D    = 32 MB
    float* kbuf = q    + (size_t)B_ * S_ * D_;        // B*S*KV   =  8 MB
    float* vbuf = kbuf + (size_t)B_ * S_ * KV_;       // B*S*KV   =  8 MB

    const int M = B_ * S_;   // 2048

    // QKV projections
    gemm_bias_kernel<<<dim3(D_ / 64, M / 64), 256, 0, stream>>>(x, wq, bq, q,    M, D_,  D_);
    gemm_bias_kernel<<<dim3(KV_ / 64, M / 64), 256, 0, stream>>>(x, wk, bk, kbuf, M, KV_, D_);
    gemm_bias_kernel<<<dim3(KV_ / 64, M / 64), 256, 0, stream>>>(x, wv, bv, vbuf, M, KV_, D_);

    // RoPE: fold both HD^-0.5 factors (q*scale, logits*scale) into q: 1/HD
    const int tq = B_ * S_ * H_ * 64;
    rope_kernel<<<(tq + 255) / 256, 256, 0, stream>>>(q, H_, 1.f / (float)HD_);
    const int tk = B_ * S_ * G_ * 64;
    rope_kernel<<<(tk + 255) / 256, 256, 0, stream>>>(kbuf, G_, 1.f);

    // Attention, in place into q
    attn_kernel<<<dim3(S_, H_, B_), 128, 0, stream>>>(kbuf, vbuf, q);

    // Output projection
    gemm_bias_kernel<<<dim3(D_ / 64, M / 64), 256, 0, stream>>>(q, wo, bo, out, M, D_, D_);
}

// Round 3
// 1099.930 us; speedup vs baseline: 4.2665x; 4.2665x over previous
//
#include <hip/hip_runtime.h>
#include <math.h>

typedef unsigned short ushort_t;
typedef __attribute__((ext_vector_type(8))) short bf16x8;
typedef __attribute__((ext_vector_type(4))) float f32x4;
typedef __attribute__((ext_vector_type(4))) unsigned short us4;
typedef __attribute__((ext_vector_type(8))) unsigned short us8;

#define B_   4
#define S_   512
#define D_   4096
#define H_   32
#define G_   8
#define HD_  128
#define KV_  1024
#define M_   (B_ * S_)   // 2048

__device__ __forceinline__ float bf2f(ushort_t u) {
    union { unsigned u; float f; } x; x.u = ((unsigned)u) << 16; return x.f;
}
__device__ __forceinline__ ushort_t f2bf(float f) {
    union { float f; unsigned u; } x; x.f = f;
    unsigned r = x.u + 0x7fffu + ((x.u >> 16) & 1u);   // round-to-nearest-even
    return (ushort_t)(r >> 16);
}

typedef const __attribute__((address_space(1))) void* gptr_t;
typedef __attribute__((address_space(3))) void* ldsptr_t;

__device__ __forceinline__ void gload_lds16(const void* g, void* lds) {
    __builtin_amdgcn_global_load_lds((gptr_t)g, (ldsptr_t)lds, 16, 0, 0);
}

// ---------------- fp32 -> bf16 elementwise ----------------
__global__ void xconv(const float* __restrict__ x, ushort_t* __restrict__ xb, int n8)
{
    const int i = blockIdx.x * blockDim.x + threadIdx.x;
    if (i >= n8) return;
    const float4 a = *(const float4*)&x[(size_t)i * 8];
    const float4 b = *(const float4*)&x[(size_t)i * 8 + 4];
    us8 o;
    o[0] = f2bf(a.x); o[1] = f2bf(a.y); o[2] = f2bf(a.z); o[3] = f2bf(a.w);
    o[4] = f2bf(b.x); o[5] = f2bf(b.y); o[6] = f2bf(b.z); o[7] = f2bf(b.w);
    *(us8*)&xb[(size_t)i * 8] = o;
}

// ---------------- W [K][N] fp32 -> Wt [N][K] bf16 ----------------
__global__ __launch_bounds__(256) void wconv(
    const float* __restrict__ W, ushort_t* __restrict__ Wt, int K, int N)
{
    __shared__ float t[32][33];
    const int n0 = blockIdx.x * 32, k0 = blockIdx.y * 32;
    const int tid = threadIdx.x;
    const int r = tid >> 3, c4 = (tid & 7) * 4;
    const float4 v = *(const float4*)&W[(size_t)(k0 + r) * N + n0 + c4];
    t[r][c4 + 0] = v.x; t[r][c4 + 1] = v.y; t[r][c4 + 2] = v.z; t[r][c4 + 3] = v.w;
    __syncthreads();
    us4 o;
    o.x = f2bf(t[c4 + 0][r]);
    o.y = f2bf(t[c4 + 1][r]);
    o.z = f2bf(t[c4 + 2][r]);
    o.w = f2bf(t[c4 + 3][r]);
    *(us4*)&Wt[(size_t)(n0 + r) * K + k0 + c4] = o;
}

// ---------------- bf16 MFMA GEMM: C[M,N] = A[M,K] @ Bt[N,K]^T + bias ----------------
// 128x128 tile, BK=32, 4 waves each computing 64x64 (4x4 fragments 16x16x32).
// LDS tiles row-major [128][32] bf16 with 16B-quarter XOR swizzle (kq ^= row&3),
// applied identically on the global_load_lds source and the ds_read side.
template<int OUT_BF16>
__global__ __launch_bounds__(256) void gemm_mfma(
    const ushort_t* __restrict__ A,   // [M][K] bf16
    const ushort_t* __restrict__ Bt,  // [N][K] bf16
    const float* __restrict__ bias,   // [N]
    float* __restrict__ Cf, ushort_t* __restrict__ Cb,
    int M, int N, int K)
{
    __shared__ ushort_t sA[128 * 32];
    __shared__ ushort_t sB[128 * 32];

    const int tid = threadIdx.x;
    const int lane = tid & 63;
    const int w = tid >> 6;
    const int m0 = blockIdx.y * 128, n0 = blockIdx.x * 128;

    const int lr = lane & 15, kg = lane >> 4;
    const int wm0 = (w >> 1) * 64, wn0 = (w & 1) * 64;

    // staging: chunk c covers LDS rows [c*16, c*16+16); lane -> row c*16 + lane/4, quarter lane&3
    const int cA0 = w * 2, cA1 = w * 2 + 1;
    const int rsub = lane >> 2, kq = lane & 3;

    f32x4 acc[4][4];
    #pragma unroll
    for (int i = 0; i < 4; ++i)
        #pragma unroll
        for (int j = 0; j < 4; ++j)
            acc[i][j] = (f32x4){0.f, 0.f, 0.f, 0.f};

    for (int k0 = 0; k0 < K; k0 += 32) {
        __syncthreads();
        {
            int row = cA0 * 16 + rsub;
            int qs = kq ^ (row & 3);
            gload_lds16(A + (size_t)(m0 + row) * K + k0 + qs * 8, (char*)sA + cA0 * 1024);
            row = cA1 * 16 + rsub;
            qs = kq ^ (row & 3);
            gload_lds16(A + (size_t)(m0 + row) * K + k0 + qs * 8, (char*)sA + cA1 * 1024);
            row = cA0 * 16 + rsub;
            qs = kq ^ (row & 3);
            gload_lds16(Bt + (size_t)(n0 + row) * K + k0 + qs * 8, (char*)sB + cA0 * 1024);
            row = cA1 * 16 + rsub;
            qs = kq ^ (row & 3);
            gload_lds16(Bt + (size_t)(n0 + row) * K + k0 + qs * 8, (char*)sB + cA1 * 1024);
        }
        __syncthreads();

        bf16x8 af[4], bfr[4];
        #pragma unroll
        for (int i = 0; i < 4; ++i) {
            int r = wm0 + i * 16 + lr;
            af[i] = *(const bf16x8*)((const char*)sA + r * 64 + ((kg ^ (r & 3)) << 4));
            r = wn0 + i * 16 + lr;
            bfr[i] = *(const bf16x8*)((const char*)sB + r * 64 + ((kg ^ (r & 3)) << 4));
        }
        #pragma unroll
        for (int i = 0; i < 4; ++i)
            #pragma unroll
            for (int j = 0; j < 4; ++j)
                acc[i][j] = __builtin_amdgcn_mfma_f32_16x16x32_bf16(af[i], bfr[j], acc[i][j], 0, 0, 0);
    }

    #pragma unroll
    for (int i = 0; i < 4; ++i) {
        #pragma unroll
        for (int j = 0; j < 4; ++j) {
            const int n = n0 + wn0 + j * 16 + lr;
            const float bs = bias[n];
            const int mbase = m0 + wm0 + i * 16 + kg * 4;   // C/D: col=lane&15, row=(lane>>4)*4+reg
            #pragma unroll
            for (int r = 0; r < 4; ++r) {
                const float val = acc[i][j][r] + bs;
                if (OUT_BF16) Cb[(size_t)(mbase + r) * N + n] = f2bf(val);
                else          Cf[(size_t)(mbase + r) * N + n] = val;
            }
        }
    }
}

// ---------------- RoPE in place on bf16 buffer ----------------
__global__ void rope_bf16(ushort_t* __restrict__ buf, int nh, float scale)
{
    const int i = blockIdx.x * blockDim.x + threadIdx.x;
    const int total = B_ * S_ * nh * 64;
    if (i >= total) return;
    const int j     = i & 63;
    const int t2    = i >> 6;
    const int head  = t2 % nh;
    const int token = t2 / nh;
    const int s     = token % S_;
    const size_t base = ((size_t)token * nh + head) * HD_;
    const float inv = __expf(-9.210340371976184f * (2.f * j) / (float)HD_);
    const float ang = (float)s * inv;
    float sn, cs;
    __sincosf(ang, &sn, &cs);
    const float x1 = bf2f(buf[base + j]);
    const float x2 = bf2f(buf[base + j + 64]);
    buf[base + j]      = f2bf((x1 * cs - x2 * sn) * scale);
    buf[base + j + 64] = f2bf((x2 * cs + x1 * sn) * scale);
}

// ---------------- Attention: block = (b, h, 16 q-rows), 256 threads ----------------
__global__ __launch_bounds__(256) void attn_v2(
    const ushort_t* __restrict__ kb, const ushort_t* __restrict__ vb,
    ushort_t* __restrict__ qb)
{
    const int s0 = blockIdx.x * 16;
    const int h = blockIdx.y, b = blockIdx.z;
    const int g = h >> 2;
    const int tid = threadIdx.x;

    __shared__ float qs[16][132];
    __shared__ float ls[16][516];
    __shared__ float red[16][16];
    __shared__ float rowinv[16];

    for (int t = tid; t < 16 * 128; t += 256) {
        const int row = t >> 7, d = t & 127;
        qs[row][d] = bf2f(qb[((size_t)(b * S_ + s0 + row)) * D_ + h * HD_ + d]);
    }
    __syncthreads();

    // logits: thread (qi, ks) computes 32 logits; 16 threads share each K row
    const int qi = tid & 15, ks = tid >> 4;
    const ushort_t* kbase = kb + (size_t)b * S_ * KV_ + g * HD_;
    for (int it = 0; it < 32; ++it) {
        const int kp = ks * 32 + it;
        const ushort_t* krow = kbase + (size_t)kp * KV_;
        float dot = 0.f;
        #pragma unroll
        for (int d8 = 0; d8 < 16; ++d8) {
            const us8 kv = *(const us8*)(krow + d8 * 8);
            #pragma unroll
            for (int e = 0; e < 8; ++e)
                dot += qs[qi][d8 * 8 + e] * bf2f(kv[e]);
        }
        ls[qi][kp] = dot;
    }
    __syncthreads();

    // softmax over each of the 16 rows; 16 workers per row
    const int row = tid & 15, c = tid >> 4;
    float pm = -1e30f;
    for (int i2 = 0; i2 < 32; ++i2) pm = fmaxf(pm, ls[row][c * 32 + i2]);
    red[row][c] = pm;
    __syncthreads();
    float m = red[row][0];
    #pragma unroll
    for (int i2 = 1; i2 < 16; ++i2) m = fmaxf(m, red[row][i2]);
    __syncthreads();
    float psum = 0.f;
    for (int i2 = 0; i2 < 32; ++i2) {
        const int idx = c * 32 + i2;
        const float p = __expf(ls[row][idx] - m);
        ls[row][idx] = p;
        psum += p;
    }
    red[row][c] = psum;
    __syncthreads();
    if (tid < 16) {
        float ssum = 0.f;
        #pragma unroll
        for (int i2 = 0; i2 < 16; ++i2) ssum += red[tid][i2];
        rowinv[tid] = 1.f / ssum;
    }
    __syncthreads();

    // PV: thread owns dim d for 8 q-rows; p read as float4 broadcasts
    const int d = tid & 127, half = tid >> 7;
    const int qi0 = half * 8;
    const ushort_t* vbase = vb + (size_t)b * S_ * KV_ + g * HD_ + d;
    float acc[8];
    #pragma unroll
    for (int r2 = 0; r2 < 8; ++r2) acc[r2] = 0.f;
    for (int kp0 = 0; kp0 < S_; kp0 += 4) {
        float vv[4];
        #pragma unroll
        for (int t2 = 0; t2 < 4; ++t2)
            vv[t2] = bf2f(vbase[(size_t)(kp0 + t2) * KV_]);
        #pragma unroll
        for (int r2 = 0; r2 < 8; ++r2) {
            const float4 p = *(const float4*)&ls[qi0 + r2][kp0];
            acc[r2] += p.x * vv[0] + p.y * vv[1] + p.z * vv[2] + p.w * vv[3];
        }
    }
    #pragma unroll
    for (int r2 = 0; r2 < 8; ++r2) {
        const int rq = qi0 + r2;
        qb[((size_t)(b * S_ + s0 + rq)) * D_ + h * HD_ + d] = f2bf(acc[r2] * rowinv[rq]);
    }
}

extern "C" void kernel_launch(void* const* d_in, const int* in_sizes, int n_in,
                              void* d_out, int out_size, void* d_ws, size_t ws_size,
                              hipStream_t stream)
{
    const float* x  = (const float*)d_in[0];
    const float* wq = (const float*)d_in[1];
    const float* bq = (const float*)d_in[2];
    const float* wk = (const float*)d_in[3];
    const float* bk = (const float*)d_in[4];
    const float* wv = (const float*)d_in[5];
    const float* bv = (const float*)d_in[6];
    const float* wo = (const float*)d_in[7];
    const float* bo = (const float*)d_in[8];
    float* out = (float*)d_out;

    char* ws = (char*)d_ws;
    ushort_t* xb   = (ushort_t*)(ws);                      // 16 MB: x bf16 [2048][4096]
    ushort_t* w1   = (ushort_t*)(ws + (16u  << 20));       // 32 MB: wq_t then wo_t [4096][4096]
    ushort_t* wkt  = (ushort_t*)(ws + (48u  << 20));       //  8 MB: [1024][4096]
    ushort_t* wvt  = (ushort_t*)(ws + (56u  << 20));       //  8 MB
    ushort_t* qbuf = (ushort_t*)(ws + (64u  << 20));       // 16 MB: q / attn-out bf16
    ushort_t* kbuf = (ushort_t*)(ws + (80u  << 20));       //  4 MB
    ushort_t* vbuf = (ushort_t*)(ws + (84u  << 20));       //  4 MB  (total 88 MB)

    xconv<<<(M_ * D_ / 8 + 255) / 256, 256, 0, stream>>>(x, xb, M_ * D_ / 8);
    wconv<<<dim3(D_ / 32, D_ / 32), 256, 0, stream>>>(wq, w1, D_, D_);
    wconv<<<dim3(KV_ / 32, D_ / 32), 256, 0, stream>>>(wk, wkt, D_, KV_);
    wconv<<<dim3(KV_ / 32, D_ / 32), 256, 0, stream>>>(wv, wvt, D_, KV_);

    gemm_mfma<1><<<dim3(D_ / 128,  M_ / 128), 256, 0, stream>>>(xb, w1,  bq, nullptr, qbuf, M_, D_,  D_);
    gemm_mfma<1><<<dim3(KV_ / 128, M_ / 128), 256, 0, stream>>>(xb, wkt, bk, nullptr, kbuf, M_, KV_, D_);
    gemm_mfma<1><<<dim3(KV_ / 128, M_ / 128), 256, 0, stream>>>(xb, wvt, bv, nullptr, vbuf, M_, KV_, D_);

    rope_bf16<<<(B_ * S_ * H_ * 64 + 255) / 256, 256, 0, stream>>>(qbuf, H_, 1.f / 128.f);
    rope_bf16<<<(B_ * S_ * G_ * 64 + 255) / 256, 256, 0, stream>>>(kbuf, G_, 1.f);

    attn_v2<<<dim3(S_ / 16, H_, B_), 256, 0, stream>>>(kbuf, vbuf, qbuf);

    wconv<<<dim3(D_ / 32, D_ / 32), 256, 0, stream>>>(wo, w1, D_, D_);
    gemm_mfma<0><<<dim3(D_ / 128, M_ / 128), 256, 0, stream>>>(qbuf, w1, bo, out, nullptr, M_, D_, D_);
}

// Round 4
// 489.899 us; speedup vs baseline: 9.5792x; 2.2452x over previous
//
#include <hip/hip_runtime.h>
#include <math.h>

typedef unsigned short ushort_t;
typedef __attribute__((ext_vector_type(8))) short bf16x8;
typedef __attribute__((ext_vector_type(4))) float f32x4;
typedef __attribute__((ext_vector_type(4))) unsigned short us4;
typedef __attribute__((ext_vector_type(8))) unsigned short us8;

#define B_   4
#define S_   512
#define D_   4096
#define H_   32
#define G_   8
#define HD_  128
#define KV_  1024
#define M_   (B_ * S_)   // 2048

__device__ __forceinline__ float bf2f(ushort_t u) {
    union { unsigned u; float f; } x; x.u = ((unsigned)u) << 16; return x.f;
}
__device__ __forceinline__ ushort_t f2bf(float f) {
    union { float f; unsigned u; } x; x.f = f;
    unsigned r = x.u + 0x7fffu + ((x.u >> 16) & 1u);   // round-to-nearest-even
    return (ushort_t)(r >> 16);
}

typedef const __attribute__((address_space(1))) void* gptr_t;
typedef __attribute__((address_space(3))) void* ldsptr_t;

__device__ __forceinline__ void gload_lds16(const void* g, void* lds) {
    __builtin_amdgcn_global_load_lds((gptr_t)g, (ldsptr_t)lds, 16, 0, 0);
}

// ---------------- fp32 -> bf16 elementwise ----------------
__global__ void xconv(const float* __restrict__ x, ushort_t* __restrict__ xb, int n8)
{
    const int i = blockIdx.x * blockDim.x + threadIdx.x;
    if (i >= n8) return;
    const float4 a = *(const float4*)&x[(size_t)i * 8];
    const float4 b = *(const float4*)&x[(size_t)i * 8 + 4];
    us8 o;
    o[0] = f2bf(a.x); o[1] = f2bf(a.y); o[2] = f2bf(a.z); o[3] = f2bf(a.w);
    o[4] = f2bf(b.x); o[5] = f2bf(b.y); o[6] = f2bf(b.z); o[7] = f2bf(b.w);
    *(us8*)&xb[(size_t)i * 8] = o;
}

// ---------------- W [K][N] fp32 -> Wt [N][K] bf16 ----------------
__global__ __launch_bounds__(256) void wconv(
    const float* __restrict__ W, ushort_t* __restrict__ Wt, int K, int N)
{
    __shared__ float t[32][33];
    const int n0 = blockIdx.x * 32, k0 = blockIdx.y * 32;
    const int tid = threadIdx.x;
    const int r = tid >> 3, c4 = (tid & 7) * 4;
    const float4 v = *(const float4*)&W[(size_t)(k0 + r) * N + n0 + c4];
    t[r][c4 + 0] = v.x; t[r][c4 + 1] = v.y; t[r][c4 + 2] = v.z; t[r][c4 + 3] = v.w;
    __syncthreads();
    us4 o;
    o.x = f2bf(t[c4 + 0][r]);
    o.y = f2bf(t[c4 + 1][r]);
    o.z = f2bf(t[c4 + 2][r]);
    o.w = f2bf(t[c4 + 3][r]);
    *(us4*)&Wt[(size_t)(n0 + r) * K + k0 + c4] = o;
}

// ---------------- bf16 MFMA GEMM: C[M,N] = A[M,K] @ Bt[N,K]^T + bias ----------------
template<int OUT_BF16>
__global__ __launch_bounds__(256) void gemm_mfma(
    const ushort_t* __restrict__ A,   // [M][K] bf16
    const ushort_t* __restrict__ Bt,  // [N][K] bf16
    const float* __restrict__ bias,   // [N]
    float* __restrict__ Cf, ushort_t* __restrict__ Cb,
    int M, int N, int K)
{
    __shared__ ushort_t sA[128 * 32];
    __shared__ ushort_t sB[128 * 32];

    const int tid = threadIdx.x;
    const int lane = tid & 63;
    const int w = tid >> 6;
    const int m0 = blockIdx.y * 128, n0 = blockIdx.x * 128;

    const int lr = lane & 15, kg = lane >> 4;
    const int wm0 = (w >> 1) * 64, wn0 = (w & 1) * 64;

    const int cA0 = w * 2, cA1 = w * 2 + 1;
    const int rsub = lane >> 2, kq = lane & 3;

    f32x4 acc[4][4];
    #pragma unroll
    for (int i = 0; i < 4; ++i)
        #pragma unroll
        for (int j = 0; j < 4; ++j)
            acc[i][j] = (f32x4){0.f, 0.f, 0.f, 0.f};

    for (int k0 = 0; k0 < K; k0 += 32) {
        __syncthreads();
        {
            int row = cA0 * 16 + rsub;
            int qs = kq ^ (row & 3);
            gload_lds16(A + (size_t)(m0 + row) * K + k0 + qs * 8, (char*)sA + cA0 * 1024);
            row = cA1 * 16 + rsub;
            qs = kq ^ (row & 3);
            gload_lds16(A + (size_t)(m0 + row) * K + k0 + qs * 8, (char*)sA + cA1 * 1024);
            row = cA0 * 16 + rsub;
            qs = kq ^ (row & 3);
            gload_lds16(Bt + (size_t)(n0 + row) * K + k0 + qs * 8, (char*)sB + cA0 * 1024);
            row = cA1 * 16 + rsub;
            qs = kq ^ (row & 3);
            gload_lds16(Bt + (size_t)(n0 + row) * K + k0 + qs * 8, (char*)sB + cA1 * 1024);
        }
        __syncthreads();

        bf16x8 af[4], bfr[4];
        #pragma unroll
        for (int i = 0; i < 4; ++i) {
            int r = wm0 + i * 16 + lr;
            af[i] = *(const bf16x8*)((const char*)sA + r * 64 + ((kg ^ (r & 3)) << 4));
            r = wn0 + i * 16 + lr;
            bfr[i] = *(const bf16x8*)((const char*)sB + r * 64 + ((kg ^ (r & 3)) << 4));
        }
        #pragma unroll
        for (int i = 0; i < 4; ++i)
            #pragma unroll
            for (int j = 0; j < 4; ++j)
                acc[i][j] = __builtin_amdgcn_mfma_f32_16x16x32_bf16(af[i], bfr[j], acc[i][j], 0, 0, 0);
    }

    #pragma unroll
    for (int i = 0; i < 4; ++i) {
        #pragma unroll
        for (int j = 0; j < 4; ++j) {
            const int n = n0 + wn0 + j * 16 + lr;
            const float bs = bias[n];
            const int mbase = m0 + wm0 + i * 16 + kg * 4;   // C/D: col=lane&15, row=(lane>>4)*4+reg
            #pragma unroll
            for (int r = 0; r < 4; ++r) {
                const float val = acc[i][j][r] + bs;
                if (OUT_BF16) Cb[(size_t)(mbase + r) * N + n] = f2bf(val);
                else          Cf[(size_t)(mbase + r) * N + n] = val;
            }
        }
    }
}

// ---------------- RoPE in place on bf16 buffer ----------------
__global__ void rope_bf16(ushort_t* __restrict__ buf, int nh, float scale)
{
    const int i = blockIdx.x * blockDim.x + threadIdx.x;
    const int total = B_ * S_ * nh * 64;
    if (i >= total) return;
    const int j     = i & 63;
    const int t2    = i >> 6;
    const int head  = t2 % nh;
    const int token = t2 / nh;
    const int s     = token % S_;
    const size_t base = ((size_t)token * nh + head) * HD_;
    const float inv = __expf(-9.210340371976184f * (2.f * j) / (float)HD_);
    const float ang = (float)s * inv;
    float sn, cs;
    __sincosf(ang, &sn, &cs);
    const float x1 = bf2f(buf[base + j]);
    const float x2 = bf2f(buf[base + j + 64]);
    buf[base + j]      = f2bf((x1 * cs - x2 * sn) * scale);
    buf[base + j + 64] = f2bf((x2 * cs + x1 * sn) * scale);
}

// ---------------- V transpose: [B*S][KV] -> [B*G][HD][S] ----------------
__global__ __launch_bounds__(256) void vtrans(
    const ushort_t* __restrict__ vb, ushort_t* __restrict__ vT)
{
    __shared__ ushort_t t[32][40];
    const int s0 = blockIdx.x * 32;
    const int d0 = blockIdx.y * 32;
    const int bg = blockIdx.z;                 // b*G + g
    const int b = bg >> 3, g = bg & 7;
    const int tid = threadIdx.x;
    const int row = tid >> 3, c4 = (tid & 7) * 4;
    const us4 v = *(const us4*)&vb[(size_t)(b * S_ + s0 + row) * KV_ + g * HD_ + d0 + c4];
    t[row][c4 + 0] = v.x; t[row][c4 + 1] = v.y;
    t[row][c4 + 2] = v.z; t[row][c4 + 3] = v.w;
    __syncthreads();
    us4 o;
    o.x = t[c4 + 0][row]; o.y = t[c4 + 1][row];
    o.z = t[c4 + 2][row]; o.w = t[c4 + 3][row];
    *(us4*)&vT[(size_t)(bg * HD_ + d0 + row) * S_ + s0 + c4] = o;
}

// ---------------- MFMA attention: block = (b, h, 64 q-rows), 4 waves ----------------
// Wave w owns q-rows [q0+w*16, q0+w*16+16). Full 512 logits kept in registers
// (32 f32x4/lane). P (unnormalized, bf16) goes to per-wave swizzled LDS for PV.
__global__ __launch_bounds__(256) void attn_mfma(
    const ushort_t* __restrict__ kb,   // [B*S][KV] bf16 (rope'd)
    const ushort_t* __restrict__ vT,   // [B*G][HD][S] bf16
    ushort_t* __restrict__ qb)         // [B*S][D] bf16, in/out (rope'd+scaled q)
{
    __shared__ ushort_t sKV[8192];          // 16 KB staging (K chunk or V^T chunk)
    __shared__ ushort_t sP[4 * 16 * 512];   // 64 KB: per-wave P [16 q][512 k]

    const int q0 = blockIdx.x * 64;
    const int h = blockIdx.y, b = blockIdx.z;
    const int g = h >> 2;
    const int tid = threadIdx.x;
    const int lane = tid & 63, w = tid >> 6;
    const int lr = lane & 15, kg = lane >> 4;

    // Q fragments straight from global (row = lane's q-row, k-window c)
    bf16x8 af[4];
    {
        const ushort_t* qrow = qb + (size_t)(b * S_ + q0 + w * 16 + lr) * D_ + h * HD_;
        #pragma unroll
        for (int c = 0; c < 4; ++c)
            af[c] = *(const bf16x8*)(qrow + c * 32 + kg * 8);
    }

    f32x4 l[8][4];
    #pragma unroll
    for (int ch = 0; ch < 8; ++ch)
        #pragma unroll
        for (int t = 0; t < 4; ++t)
            l[ch][t] = (f32x4){0.f, 0.f, 0.f, 0.f};

    // ---- QK^T: 8 chunks of 64 keys ----
    const ushort_t* kbase = kb + (size_t)b * S_ * KV_ + g * HD_;
    #pragma unroll
    for (int ch = 0; ch < 8; ++ch) {
        __syncthreads();
        #pragma unroll
        for (int i = 0; i < 4; ++i) {
            const int o = w * 4096 + i * 1024;        // wave-uniform LDS byte base
            const int key = (o >> 8) + (lane >> 4);   // dest row for this lane
            const int sl = lane & 15;                 // dest 16B slot
            gload_lds16(kbase + (size_t)(ch * 64 + key) * KV_ + ((sl ^ (key & 15)) * 8),
                        (char*)sKV + o);
        }
        __syncthreads();
        #pragma unroll
        for (int t = 0; t < 4; ++t) {
            const int key = t * 16 + lr;
            #pragma unroll
            for (int c = 0; c < 4; ++c) {
                const bf16x8 bf = *(const bf16x8*)((const char*)sKV + key * 256 +
                                                   (((c * 4 + kg) ^ (key & 15)) << 4));
                l[ch][t] = __builtin_amdgcn_mfma_f32_16x16x32_bf16(af[c], bf, l[ch][t], 0, 0, 0);
            }
        }
    }

    // ---- softmax (rows q = kg*4+r live in this lane; reduce across 16 lanes) ----
    float inv[4];
    #pragma unroll
    for (int r = 0; r < 4; ++r) {
        float m = -1e30f;
        #pragma unroll
        for (int ch = 0; ch < 8; ++ch)
            #pragma unroll
            for (int t = 0; t < 4; ++t)
                m = fmaxf(m, l[ch][t][r]);
        #pragma unroll
        for (int msk = 1; msk <= 8; msk <<= 1)
            m = fmaxf(m, __shfl_xor(m, msk));
        float s = 0.f;
        const int q = kg * 4 + r;
        #pragma unroll
        for (int ch = 0; ch < 8; ++ch)
            #pragma unroll
            for (int t = 0; t < 4; ++t) {
                const float p = __expf(l[ch][t][r] - m);
                s += p;
                const int gs = ch * 8 + t * 2 + (lr >> 3);     // key-slot (8 keys)
                sP[w * 8192 + q * 512 + ((gs ^ q) << 3) + (lr & 7)] = f2bf(p);
            }
        #pragma unroll
        for (int msk = 1; msk <= 8; msk <<= 1)
            s += __shfl_xor(s, msk);
        inv[r] = 1.f / s;
    }

    // ---- PV: 8 chunks of 64 keys from V^T ----
    f32x4 oacc[8];
    #pragma unroll
    for (int dt = 0; dt < 8; ++dt) oacc[dt] = (f32x4){0.f, 0.f, 0.f, 0.f};

    const ushort_t* vbase = vT + (size_t)(b * G_ + g) * HD_ * S_;
    for (int ch = 0; ch < 8; ++ch) {
        __syncthreads();
        #pragma unroll
        for (int i = 0; i < 4; ++i) {
            const int o = w * 4096 + i * 1024;
            const int d = (o >> 7) + (lane >> 3);    // dest V^T row
            const int sl = lane & 7;
            gload_lds16(vbase + (size_t)d * S_ + ch * 64 + ((sl ^ (d & 7)) * 8),
                        (char*)sKV + o);
        }
        __syncthreads();
        #pragma unroll
        for (int c2 = 0; c2 < 2; ++c2) {
            const int gs = ch * 8 + c2 * 4 + kg;
            const bf16x8 ap = *(const bf16x8*)((const char*)sP + w * 16384 + lr * 1024 +
                                               ((gs ^ lr) << 4));
            #pragma unroll
            for (int dt = 0; dt < 8; ++dt) {
                const int d = dt * 16 + lr;
                const bf16x8 bv = *(const bf16x8*)((const char*)sKV + d * 128 +
                                                   (((c2 * 4 + kg) ^ (d & 7)) << 4));
                oacc[dt] = __builtin_amdgcn_mfma_f32_16x16x32_bf16(ap, bv, oacc[dt], 0, 0, 0);
            }
        }
    }

    // ---- epilogue: scale by 1/sum, write back over q ----
    #pragma unroll
    for (int dt = 0; dt < 8; ++dt) {
        #pragma unroll
        for (int r = 0; r < 4; ++r) {
            const int q = kg * 4 + r;
            qb[(size_t)(b * S_ + q0 + w * 16 + q) * D_ + h * HD_ + dt * 16 + lr] =
                f2bf(oacc[dt][r] * inv[r]);
        }
    }
}

extern "C" void kernel_launch(void* const* d_in, const int* in_sizes, int n_in,
                              void* d_out, int out_size, void* d_ws, size_t ws_size,
                              hipStream_t stream)
{
    const float* x  = (const float*)d_in[0];
    const float* wq = (const float*)d_in[1];
    const float* bq = (const float*)d_in[2];
    const float* wk = (const float*)d_in[3];
    const float* bk = (const float*)d_in[4];
    const float* wv = (const float*)d_in[5];
    const float* bv = (const float*)d_in[6];
    const float* wo = (const float*)d_in[7];
    const float* bo = (const float*)d_in[8];
    float* out = (float*)d_out;

    char* ws = (char*)d_ws;
    ushort_t* xb   = (ushort_t*)(ws);                      // 16 MB: x bf16 [2048][4096]
    ushort_t* w1   = (ushort_t*)(ws + (16u  << 20));       // 32 MB: wq_t then wo_t
    ushort_t* wkt  = (ushort_t*)(ws + (48u  << 20));       //  8 MB: wk_t; later vT (4 MB)
    ushort_t* wvt  = (ushort_t*)(ws + (56u  << 20));       //  8 MB: wv_t
    ushort_t* qbuf = (ushort_t*)(ws + (64u  << 20));       // 16 MB: q / attn-out bf16
    ushort_t* kbuf = (ushort_t*)(ws + (80u  << 20));       //  4 MB
    ushort_t* vbuf = (ushort_t*)(ws + (84u  << 20));       //  4 MB  (total 88 MB)
    ushort_t* vT   = wkt;                                  // reuse after K GEMM

    xconv<<<(M_ * D_ / 8 + 255) / 256, 256, 0, stream>>>(x, xb, M_ * D_ / 8);
    wconv<<<dim3(D_ / 32, D_ / 32), 256, 0, stream>>>(wq, w1, D_, D_);
    wconv<<<dim3(KV_ / 32, D_ / 32), 256, 0, stream>>>(wk, wkt, D_, KV_);
    wconv<<<dim3(KV_ / 32, D_ / 32), 256, 0, stream>>>(wv, wvt, D_, KV_);

    gemm_mfma<1><<<dim3(D_ / 128,  M_ / 128), 256, 0, stream>>>(xb, w1,  bq, nullptr, qbuf, M_, D_,  D_);
    gemm_mfma<1><<<dim3(KV_ / 128, M_ / 128), 256, 0, stream>>>(xb, wkt, bk, nullptr, kbuf, M_, KV_, D_);
    gemm_mfma<1><<<dim3(KV_ / 128, M_ / 128), 256, 0, stream>>>(xb, wvt, bv, nullptr, vbuf, M_, KV_, D_);

    // V^T into the (now dead) wk_t region
    vtrans<<<dim3(S_ / 32, HD_ / 32, B_ * G_), 256, 0, stream>>>(vbuf, vT);

    rope_bf16<<<(B_ * S_ * H_ * 64 + 255) / 256, 256, 0, stream>>>(qbuf, H_, 1.f / 128.f);
    rope_bf16<<<(B_ * S_ * G_ * 64 + 255) / 256, 256, 0, stream>>>(kbuf, G_, 1.f);

    attn_mfma<<<dim3(S_ / 64, H_, B_), 256, 0, stream>>>(kbuf, vT, qbuf);

    wconv<<<dim3(D_ / 32, D_ / 32), 256, 0, stream>>>(wo, w1, D_, D_);
    gemm_mfma<0><<<dim3(D_ / 128, M_ / 128), 256, 0, stream>>>(qbuf, w1, bo, out, nullptr, M_, D_, D_);
}

// Round 6
// 350.122 us; speedup vs baseline: 13.4034x; 1.3992x over previous
//
#include <hip/hip_runtime.h>
#include <math.h>

typedef unsigned short ushort_t;
typedef __attribute__((ext_vector_type(8))) short bf16x8;
typedef __attribute__((ext_vector_type(4))) float f32x4;
typedef __attribute__((ext_vector_type(4))) unsigned short us4;
typedef __attribute__((ext_vector_type(8))) unsigned short us8;

#define B_   4
#define S_   512
#define D_   4096
#define H_   32
#define G_   8
#define HD_  128
#define KV_  1024
#define M_   (B_ * S_)   // 2048
#define QN_  6144        // fused QKV column count

__device__ __forceinline__ float bf2f(ushort_t u) {
    union { unsigned u; float f; } x; x.u = ((unsigned)u) << 16; return x.f;
}
__device__ __forceinline__ ushort_t f2bf(float f) {
    union { float f; unsigned u; } x; x.f = f;
    unsigned r = x.u + 0x7fffu + ((x.u >> 16) & 1u);   // round-to-nearest-even
    return (ushort_t)(r >> 16);
}

typedef const __attribute__((address_space(1))) void* gptr_t;
typedef __attribute__((address_space(3))) void* ldsptr_t;

__device__ __forceinline__ void gload_lds16(const void* g, void* lds) {
    __builtin_amdgcn_global_load_lds((gptr_t)g, (ldsptr_t)lds, 16, 0, 0);
}

#define BAR() asm volatile("s_barrier" ::: "memory")
#define LGKM0() do { asm volatile("s_waitcnt lgkmcnt(0)" ::: "memory"); \
                     __builtin_amdgcn_sched_barrier(0); } while (0)

// ---------------- fp32 -> bf16 elementwise ----------------
__global__ void xconv(const float* __restrict__ x, ushort_t* __restrict__ xb, int n8)
{
    const int i = blockIdx.x * blockDim.x + threadIdx.x;
    if (i >= n8) return;
    const float4 a = *(const float4*)&x[(size_t)i * 8];
    const float4 b = *(const float4*)&x[(size_t)i * 8 + 4];
    us8 o;
    o[0] = f2bf(a.x); o[1] = f2bf(a.y); o[2] = f2bf(a.z); o[3] = f2bf(a.w);
    o[4] = f2bf(b.x); o[5] = f2bf(b.y); o[6] = f2bf(b.z); o[7] = f2bf(b.w);
    *(us8*)&xb[(size_t)i * 8] = o;
}

// ---------------- W [K][N] fp32 -> Wt [N][K] bf16 ----------------
__global__ __launch_bounds__(256) void wconv(
    const float* __restrict__ W, ushort_t* __restrict__ Wt, int K, int N)
{
    __shared__ float t[32][33];
    const int n0 = blockIdx.x * 32, k0 = blockIdx.y * 32;
    const int tid = threadIdx.x;
    const int r = tid >> 3, c4 = (tid & 7) * 4;
    const float4 v = *(const float4*)&W[(size_t)(k0 + r) * N + n0 + c4];
    t[r][c4 + 0] = v.x; t[r][c4 + 1] = v.y; t[r][c4 + 2] = v.z; t[r][c4 + 3] = v.w;
    __syncthreads();
    us4 o;
    o.x = f2bf(t[c4 + 0][r]);
    o.y = f2bf(t[c4 + 1][r]);
    o.z = f2bf(t[c4 + 2][r]);
    o.w = f2bf(t[c4 + 3][r]);
    *(us4*)&Wt[(size_t)(n0 + r) * K + k0 + c4] = o;
}

// ============ 256x256 8-phase MFMA GEMM (T1+T2+T3+T4+T5) ============
// C[M,N] = A[M,K] @ Bt[N,K]^T + bias.  BK=64, 8 waves (2M x 4N),
// per-wave C = 128x64 (8x4 frags of 16x16), 64 MFMA per K-tile per wave.
// LDS: double-buffered A[256][64] + B[256][64] bf16 = 128 KiB.
// Fragment row maps ALIGN with staging halves (fix for round-5 race):
//   A frag row = mi*32 + wr*16 + lr  -> mi 0-3 == A-lo (P1), mi 4-7 == A-hi (P3)
//   B frag row = ni*64 + wc*16 + lr  -> ni 0-1 == B-lo (P1), ni 2-3 == B-hi (P2)
// Ledger: A-lo(t) readers done P1, staged P2(t+2); B-lo done P1, staged P3(t+2);
// B-hi done P2, staged P4(t+2); A-hi(t+1) -> opposite buffer at P1.
// vmcnt(6) at P4 retires through A-hi(t+1) => tile t+1 landed before its P1.
template<int OUT_BF16>
__global__ __launch_bounds__(512, 2) void gemm8(
    const ushort_t* __restrict__ A, int lda,
    const ushort_t* __restrict__ Bt,
    const float* __restrict__ bias0, const float* __restrict__ bias1,
    const float* __restrict__ bias2,
    float* __restrict__ Cf, ushort_t* __restrict__ Cb,
    int M, int N, int K)
{
    __shared__ ushort_t sA[2][256 * 64];   // 64 KiB
    __shared__ ushort_t sB[2][256 * 64];   // 64 KiB

    const int tid = threadIdx.x;
    const int lane = tid & 63, w = tid >> 6;
    const int lr = lane & 15, kg = lane >> 4;
    const int wr = w >> 2, wc = w & 3;

    // T1: XCD-aware swizzle (grids here are multiples of 8)
    const int nwg = gridDim.x;
    const int cpx = nwg >> 3;
    const int bid = (blockIdx.x & 7) * cpx + (blockIdx.x >> 3);
    const int nbx = N >> 8;
    const int bx = bid % nbx, by = bid / nbx;
    const int bm0 = by << 8, bn0 = bx << 8;

    const int NT = K >> 6;

    // half h: 0=A-lo 1=A-hi 2=B-lo 3=B-hi -> buf t&1
    auto stage = [&](int t, int h) {
        const int c = t & 1;
        const ushort_t* gb; int ld; char* sbase;
        if (h < 2) { gb = A + (size_t)bm0 * lda; ld = lda; sbase = (char*)sA; }
        else       { gb = Bt + (size_t)bn0 * K;  ld = K;   sbase = (char*)sB; }
        const int half = h & 1;
        #pragma unroll
        for (int j = 0; j < 2; ++j) {
            const int o = j * 8192 + tid * 16;       // byte within 16KB half
            const int row = half * 128 + (o >> 7);   // tile row
            const int slot = (o >> 4) & 7;
            gload_lds16(gb + (size_t)row * ld + t * 64 + ((slot ^ (row & 7)) << 3),
                        sbase + c * 32768 + half * 16384 + j * 8192 + w * 1024);
        }
    };
    auto lda_frag = [&](int c, int mi, int s) {
        const int row = mi * 32 + wr * 16 + lr;
        return *(const bf16x8*)((const char*)sA + c * 32768 + row * 128 +
                                (((s * 4 + kg) ^ (row & 7)) << 4));
    };
    auto ldb_frag = [&](int c, int ni, int s) {
        const int row = ni * 64 + wc * 16 + lr;
        return *(const bf16x8*)((const char*)sB + c * 32768 + row * 128 +
                                (((s * 4 + kg) ^ (row & 7)) << 4));
    };

    f32x4 acc[8][4];
    #pragma unroll
    for (int i = 0; i < 8; ++i)
        #pragma unroll
        for (int j = 0; j < 4; ++j)
            acc[i][j] = (f32x4){0.f, 0.f, 0.f, 0.f};

    // prologue: 7 halves in flight, confirm tile 0 (vmcnt 6 = 3 halves out)
    stage(0, 0); stage(0, 2); stage(0, 3); stage(0, 1);
    stage(1, 0); stage(1, 2); stage(1, 3);
    asm volatile("s_waitcnt vmcnt(6)" ::: "memory");
    BAR();

    for (int t = 0; t < NT; ++t) {
        const int c = t & 1;
        bf16x8 a[4][2], b[4][2];

        // ---- P1: quad (0,0): A-lo x B-lo ----
        #pragma unroll
        for (int mi = 0; mi < 4; ++mi)
            #pragma unroll
            for (int s = 0; s < 2; ++s) a[mi][s] = lda_frag(c, mi, s);
        #pragma unroll
        for (int ni = 0; ni < 2; ++ni)
            #pragma unroll
            for (int s = 0; s < 2; ++s) b[ni][s] = ldb_frag(c, ni, s);
        if (t + 1 < NT) stage(t + 1, 1);
        BAR();
        LGKM0();
        __builtin_amdgcn_s_setprio(1);
        #pragma unroll
        for (int mi = 0; mi < 4; ++mi)
            #pragma unroll
            for (int ni = 0; ni < 2; ++ni)
                #pragma unroll
                for (int s = 0; s < 2; ++s)
                    acc[mi][ni] = __builtin_amdgcn_mfma_f32_16x16x32_bf16(
                        a[mi][s], b[ni][s], acc[mi][ni], 0, 0, 0);
        __builtin_amdgcn_s_setprio(0);
        BAR();

        // ---- P2: quad (0,1): A-lo x B-hi ----
        #pragma unroll
        for (int ni = 2; ni < 4; ++ni)
            #pragma unroll
            for (int s = 0; s < 2; ++s) b[ni][s] = ldb_frag(c, ni, s);
        if (t + 2 < NT) stage(t + 2, 0);
        BAR();
        LGKM0();
        __builtin_amdgcn_s_setprio(1);
        #pragma unroll
        for (int mi = 0; mi < 4; ++mi)
            #pragma unroll
            for (int ni = 2; ni < 4; ++ni)
                #pragma unroll
                for (int s = 0; s < 2; ++s)
                    acc[mi][ni] = __builtin_amdgcn_mfma_f32_16x16x32_bf16(
                        a[mi][s], b[ni][s], acc[mi][ni], 0, 0, 0);
        __builtin_amdgcn_s_setprio(0);
        BAR();

        // ---- P3: quad (1,1): A-hi x B-hi ----
        #pragma unroll
        for (int mi = 0; mi < 4; ++mi)
            #pragma unroll
            for (int s = 0; s < 2; ++s) a[mi][s] = lda_frag(c, mi + 4, s);
        if (t + 2 < NT) stage(t + 2, 2);
        BAR();
        LGKM0();
        __builtin_amdgcn_s_setprio(1);
        #pragma unroll
        for (int mi = 0; mi < 4; ++mi)
            #pragma unroll
            for (int ni = 2; ni < 4; ++ni)
                #pragma unroll
                for (int s = 0; s < 2; ++s)
                    acc[mi + 4][ni] = __builtin_amdgcn_mfma_f32_16x16x32_bf16(
                        a[mi][s], b[ni][s], acc[mi + 4][ni], 0, 0, 0);
        __builtin_amdgcn_s_setprio(0);
        BAR();

        // ---- P4: quad (1,0): A-hi x B-lo ----
        if (t + 2 < NT) {
            stage(t + 2, 3);
            asm volatile("s_waitcnt vmcnt(6)" ::: "memory");
        } else {
            asm volatile("s_waitcnt vmcnt(0)" ::: "memory");
        }
        BAR();
        __builtin_amdgcn_s_setprio(1);
        #pragma unroll
        for (int mi = 0; mi < 4; ++mi)
            #pragma unroll
            for (int ni = 0; ni < 2; ++ni)
                #pragma unroll
                for (int s = 0; s < 2; ++s)
                    acc[mi + 4][ni] = __builtin_amdgcn_mfma_f32_16x16x32_bf16(
                        a[mi][s], b[ni][s], acc[mi + 4][ni], 0, 0, 0);
        __builtin_amdgcn_s_setprio(0);
        BAR();
    }

    // ---- epilogue ----
    #pragma unroll
    for (int mi = 0; mi < 8; ++mi) {
        #pragma unroll
        for (int ni = 0; ni < 4; ++ni) {
            const int n = bn0 + ni * 64 + wc * 16 + lr;
            const float bs = (n < 4096) ? bias0[n]
                           : (n < 5120) ? bias1[n - 4096] : bias2[n - 5120];
            const int mr = bm0 + mi * 32 + wr * 16 + kg * 4;
            #pragma unroll
            for (int r = 0; r < 4; ++r) {
                const float val = acc[mi][ni][r] + bs;
                if (OUT_BF16) Cb[(size_t)(mr + r) * N + n] = f2bf(val);
                else          Cf[(size_t)(mr + r) * N + n] = val;
            }
        }
    }
}

// ---------------- RoPE in place (stride QN_), buf pre-offset to col start ----
__global__ void rope_bf16(ushort_t* __restrict__ buf, int nh, float scale)
{
    const int i = blockIdx.x * blockDim.x + threadIdx.x;
    const int total = B_ * S_ * nh * 64;
    if (i >= total) return;
    const int j     = i & 63;
    const int t2    = i >> 6;
    const int head  = t2 % nh;
    const int token = t2 / nh;
    const int s     = token % S_;
    const size_t base = (size_t)token * QN_ + head * HD_;
    const float inv = __expf(-9.210340371976184f * (2.f * j) / (float)HD_);
    const float ang = (float)s * inv;
    float sn, cs;
    __sincosf(ang, &sn, &cs);
    const float x1 = bf2f(buf[base + j]);
    const float x2 = bf2f(buf[base + j + 64]);
    buf[base + j]      = f2bf((x1 * cs - x2 * sn) * scale);
    buf[base + j + 64] = f2bf((x2 * cs + x1 * sn) * scale);
}

// ---------------- V transpose: qkv v-cols -> [B*G][HD][S] ----------------
__global__ __launch_bounds__(256) void vtrans(
    const ushort_t* __restrict__ vb,   // qkv + 5120
    ushort_t* __restrict__ vT)
{
    __shared__ ushort_t t[32][40];
    const int s0 = blockIdx.x * 32;
    const int d0 = blockIdx.y * 32;
    const int bg = blockIdx.z;
    const int b = bg >> 3, g = bg & 7;
    const int tid = threadIdx.x;
    const int row = tid >> 3, c4 = (tid & 7) * 4;
    const us4 v = *(const us4*)&vb[(size_t)(b * S_ + s0 + row) * QN_ + g * HD_ + d0 + c4];
    t[row][c4 + 0] = v.x; t[row][c4 + 1] = v.y;
    t[row][c4 + 2] = v.z; t[row][c4 + 3] = v.w;
    __syncthreads();
    us4 o;
    o.x = t[c4 + 0][row]; o.y = t[c4 + 1][row];
    o.z = t[c4 + 2][row]; o.w = t[c4 + 3][row];
    *(us4*)&vT[(size_t)(bg * HD_ + d0 + row) * S_ + s0 + c4] = o;
}

// ---------------- MFMA attention: block = (b, h, 64 q-rows), 4 waves ----------------
__global__ __launch_bounds__(256) void attn_mfma(
    const ushort_t* __restrict__ kb,   // qkv + 4096 (rope'd K cols)
    const ushort_t* __restrict__ vT,   // [B*G][HD][S]
    ushort_t* __restrict__ qb)         // qkv (rope'd+scaled q cols), in/out
{
    __shared__ ushort_t sKV[8192];          // 16 KB staging
    __shared__ ushort_t sP[4 * 16 * 512];   // 64 KB per-wave P

    const int q0 = blockIdx.x * 64;
    const int h = blockIdx.y, b = blockIdx.z;
    const int g = h >> 2;
    const int tid = threadIdx.x;
    const int lane = tid & 63, w = tid >> 6;
    const int lr = lane & 15, kg = lane >> 4;

    bf16x8 af[4];
    {
        const ushort_t* qrow = qb + (size_t)(b * S_ + q0 + w * 16 + lr) * QN_ + h * HD_;
        #pragma unroll
        for (int c = 0; c < 4; ++c)
            af[c] = *(const bf16x8*)(qrow + c * 32 + kg * 8);
    }

    f32x4 l[8][4];
    #pragma unroll
    for (int ch = 0; ch < 8; ++ch)
        #pragma unroll
        for (int t = 0; t < 4; ++t)
            l[ch][t] = (f32x4){0.f, 0.f, 0.f, 0.f};

    // ---- QK^T ----
    const ushort_t* kbase = kb + (size_t)b * S_ * QN_ + g * HD_;
    #pragma unroll
    for (int ch = 0; ch < 8; ++ch) {
        __syncthreads();
        #pragma unroll
        for (int i = 0; i < 4; ++i) {
            const int o = w * 4096 + i * 1024;
            const int key = (o >> 8) + (lane >> 4);
            const int sl = lane & 15;
            gload_lds16(kbase + (size_t)(ch * 64 + key) * QN_ + ((sl ^ (key & 15)) * 8),
                        (char*)sKV + o);
        }
        __syncthreads();
        #pragma unroll
        for (int t = 0; t < 4; ++t) {
            const int key = t * 16 + lr;
            #pragma unroll
            for (int c = 0; c < 4; ++c) {
                const bf16x8 bf = *(const bf16x8*)((const char*)sKV + key * 256 +
                                                   (((c * 4 + kg) ^ (key & 15)) << 4));
                l[ch][t] = __builtin_amdgcn_mfma_f32_16x16x32_bf16(af[c], bf, l[ch][t], 0, 0, 0);
            }
        }
    }

    // ---- softmax ----
    float inv[4];
    #pragma unroll
    for (int r = 0; r < 4; ++r) {
        float m = -1e30f;
        #pragma unroll
        for (int ch = 0; ch < 8; ++ch)
            #pragma unroll
            for (int t = 0; t < 4; ++t)
                m = fmaxf(m, l[ch][t][r]);
        #pragma unroll
        for (int msk = 1; msk <= 8; msk <<= 1)
            m = fmaxf(m, __shfl_xor(m, msk));
        float s = 0.f;
        const int q = kg * 4 + r;
        #pragma unroll
        for (int ch = 0; ch < 8; ++ch)
            #pragma unroll
            for (int t = 0; t < 4; ++t) {
                const float p = __expf(l[ch][t][r] - m);
                s += p;
                const int gs = ch * 8 + t * 2 + (lr >> 3);
                sP[w * 8192 + q * 512 + ((gs ^ q) << 3) + (lr & 7)] = f2bf(p);
            }
        #pragma unroll
        for (int msk = 1; msk <= 8; msk <<= 1)
            s += __shfl_xor(s, msk);
        inv[r] = 1.f / s;
    }

    // ---- PV ----
    f32x4 oacc[8];
    #pragma unroll
    for (int dt = 0; dt < 8; ++dt) oacc[dt] = (f32x4){0.f, 0.f, 0.f, 0.f};

    const ushort_t* vbase = vT + (size_t)(b * G_ + g) * HD_ * S_;
    for (int ch = 0; ch < 8; ++ch) {
        __syncthreads();
        #pragma unroll
        for (int i = 0; i < 4; ++i) {
            const int o = w * 4096 + i * 1024;
            const int d = (o >> 7) + (lane >> 3);
            const int sl = lane & 7;
            gload_lds16(vbase + (size_t)d * S_ + ch * 64 + ((sl ^ (d & 7)) * 8),
                        (char*)sKV + o);
        }
        __syncthreads();
        #pragma unroll
        for (int c2 = 0; c2 < 2; ++c2) {
            const int gs = ch * 8 + c2 * 4 + kg;
            const bf16x8 ap = *(const bf16x8*)((const char*)sP + w * 16384 + lr * 1024 +
                                               ((gs ^ lr) << 4));
            #pragma unroll
            for (int dt = 0; dt < 8; ++dt) {
                const int d = dt * 16 + lr;
                const bf16x8 bv = *(const bf16x8*)((const char*)sKV + d * 128 +
                                                   (((c2 * 4 + kg) ^ (d & 7)) << 4));
                oacc[dt] = __builtin_amdgcn_mfma_f32_16x16x32_bf16(ap, bv, oacc[dt], 0, 0, 0);
            }
        }
    }

    #pragma unroll
    for (int dt = 0; dt < 8; ++dt) {
        #pragma unroll
        for (int r = 0; r < 4; ++r) {
            const int q = kg * 4 + r;
            qb[(size_t)(b * S_ + q0 + w * 16 + q) * QN_ + h * HD_ + dt * 16 + lr] =
                f2bf(oacc[dt][r] * inv[r]);
        }
    }
}

extern "C" void kernel_launch(void* const* d_in, const int* in_sizes, int n_in,
                              void* d_out, int out_size, void* d_ws, size_t ws_size,
                              hipStream_t stream)
{
    const float* x  = (const float*)d_in[0];
    const float* wq = (const float*)d_in[1];
    const float* bq = (const float*)d_in[2];
    const float* wk = (const float*)d_in[3];
    const float* bk = (const float*)d_in[4];
    const float* wv = (const float*)d_in[5];
    const float* bv = (const float*)d_in[6];
    const float* wo = (const float*)d_in[7];
    const float* bo = (const float*)d_in[8];
    float* out = (float*)d_out;

    char* ws = (char*)d_ws;
    ushort_t* xb   = (ushort_t*)(ws);                 // 16 MB: x bf16 [2048][4096]
    ushort_t* Wt   = (ushort_t*)(ws + (16u << 20));   // 48 MB: [6144][4096] wq|wk|wv; later wo in rows 0-4095
    ushort_t* vT   = (ushort_t*)(ws + (48u << 20));   //  4 MB: reuses dead wk rows after QKV GEMM
    ushort_t* qkv  = (ushort_t*)(ws + (64u << 20));   // 24 MB: [2048][6144] bf16
    // total 88 MB

    xconv<<<(M_ * D_ / 8 + 255) / 256, 256, 0, stream>>>(x, xb, M_ * D_ / 8);
    wconv<<<dim3(D_ / 32, D_ / 32), 256, 0, stream>>>(wq, Wt, D_, D_);
    wconv<<<dim3(KV_ / 32, D_ / 32), 256, 0, stream>>>(wk, Wt + (size_t)4096 * 4096, D_, KV_);
    wconv<<<dim3(KV_ / 32, D_ / 32), 256, 0, stream>>>(wv, Wt + (size_t)5120 * 4096, D_, KV_);

    // fused QKV projection: [2048][6144]
    gemm8<1><<<(QN_ / 256) * (M_ / 256), 512, 0, stream>>>(
        xb, D_, Wt, bq, bk, bv, nullptr, qkv, M_, QN_, D_);

    vtrans<<<dim3(S_ / 32, HD_ / 32, B_ * G_), 256, 0, stream>>>(qkv + 5120, vT);

    rope_bf16<<<(B_ * S_ * H_ * 64 + 255) / 256, 256, 0, stream>>>(qkv, H_, 1.f / 128.f);
    rope_bf16<<<(B_ * S_ * G_ * 64 + 255) / 256, 256, 0, stream>>>(qkv + 4096, G_, 1.f);

    attn_mfma<<<dim3(S_ / 64, H_, B_), 256, 0, stream>>>(qkv + 4096, vT, qkv);

    // wo -> rows 0-4095 of Wt (wq part is dead now)
    wconv<<<dim3(D_ / 32, D_ / 32), 256, 0, stream>>>(wo, Wt, D_, D_);

    gemm8<0><<<(D_ / 256) * (M_ / 256), 512, 0, stream>>>(
        qkv, QN_, Wt, bo, bo, bo, out, nullptr, M_, D_, D_);
}

// Round 7
// 327.008 us; speedup vs baseline: 14.3508x; 1.0707x over previous
//
#include <hip/hip_runtime.h>
#include <math.h>

typedef unsigned short ushort_t;
typedef __attribute__((ext_vector_type(8))) short bf16x8;
typedef __attribute__((ext_vector_type(4))) float f32x4;
typedef __attribute__((ext_vector_type(4))) unsigned short us4;
typedef __attribute__((ext_vector_type(8))) unsigned short us8;

#define B_   4
#define S_   512
#define D_   4096
#define H_   32
#define G_   8
#define HD_  128
#define KV_  1024
#define M_   (B_ * S_)   // 2048
#define QN_  6144        // fused QKV column count

__device__ __forceinline__ float bf2f(ushort_t u) {
    union { unsigned u; float f; } x; x.u = ((unsigned)u) << 16; return x.f;
}
__device__ __forceinline__ ushort_t f2bf(float f) {
    union { float f; unsigned u; } x; x.f = f;
    unsigned r = x.u + 0x7fffu + ((x.u >> 16) & 1u);   // round-to-nearest-even
    return (ushort_t)(r >> 16);
}

typedef const __attribute__((address_space(1))) void* gptr_t;
typedef __attribute__((address_space(3))) void* ldsptr_t;

__device__ __forceinline__ void gload_lds16(const void* g, void* lds) {
    __builtin_amdgcn_global_load_lds((gptr_t)g, (ldsptr_t)lds, 16, 0, 0);
}

#define BAR() asm volatile("s_barrier" ::: "memory")
#define LGKM0() do { asm volatile("s_waitcnt lgkmcnt(0)" ::: "memory"); \
                     __builtin_amdgcn_sched_barrier(0); } while (0)

// ---------------- fp32 -> bf16 elementwise ----------------
__global__ void xconv(const float* __restrict__ x, ushort_t* __restrict__ xb, int n8)
{
    const int i = blockIdx.x * blockDim.x + threadIdx.x;
    if (i >= n8) return;
    const float4 a = *(const float4*)&x[(size_t)i * 8];
    const float4 b = *(const float4*)&x[(size_t)i * 8 + 4];
    us8 o;
    o[0] = f2bf(a.x); o[1] = f2bf(a.y); o[2] = f2bf(a.z); o[3] = f2bf(a.w);
    o[4] = f2bf(b.x); o[5] = f2bf(b.y); o[6] = f2bf(b.z); o[7] = f2bf(b.w);
    *(us8*)&xb[(size_t)i * 8] = o;
}

// ---------------- W [K][N] fp32 -> Wt [N][K] bf16 ----------------
__global__ __launch_bounds__(256) void wconv(
    const float* __restrict__ W, ushort_t* __restrict__ Wt, int K, int N)
{
    __shared__ float t[32][33];
    const int n0 = blockIdx.x * 32, k0 = blockIdx.y * 32;
    const int tid = threadIdx.x;
    const int r = tid >> 3, c4 = (tid & 7) * 4;
    const float4 v = *(const float4*)&W[(size_t)(k0 + r) * N + n0 + c4];
    t[r][c4 + 0] = v.x; t[r][c4 + 1] = v.y; t[r][c4 + 2] = v.z; t[r][c4 + 3] = v.w;
    __syncthreads();
    us4 o;
    o.x = f2bf(t[c4 + 0][r]);
    o.y = f2bf(t[c4 + 1][r]);
    o.z = f2bf(t[c4 + 2][r]);
    o.w = f2bf(t[c4 + 3][r]);
    *(us4*)&Wt[(size_t)(n0 + r) * K + k0 + c4] = o;
}

// ============ 256x256 8-phase MFMA GEMM (T1+T2+T3+T4+T5) ============
// C[M,N] = A[M,K] @ Bt[N,K]^T + bias.  BK=64, 8 waves (2M x 4N),
// per-wave C = 128x64 (8x4 frags of 16x16), 64 MFMA per K-tile per wave.
// Fragment row maps align with staging halves:
//   A frag row = mi*32 + wr*16 + lr  -> mi 0-3 == A-lo (P1), mi 4-7 == A-hi (P3)
//   B frag row = ni*64 + wc*16 + lr  -> ni 0-1 == B-lo (P1), ni 2-3 == B-hi (P2)
// SPLITK: grid doubles; swizzled bid>>7 selects K-half. khalf0 writes Cf+bias,
// khalf1 writes raw fp32 partial to P0 (rows 0-1023) / P1 (rows 1024-2047).
template<int OUT_BF16, int SPLITK>
__global__ __launch_bounds__(512, 2) void gemm8(
    const ushort_t* __restrict__ A, int lda,
    const ushort_t* __restrict__ Bt, int ldb,
    const float* __restrict__ bias0, const float* __restrict__ bias1,
    const float* __restrict__ bias2,
    float* __restrict__ Cf, ushort_t* __restrict__ Cb,
    float* __restrict__ P0, float* __restrict__ P1,
    int M, int N, int K)
{
    __shared__ ushort_t sA[2][256 * 64];   // 64 KiB
    __shared__ ushort_t sB[2][256 * 64];   // 64 KiB

    const int tid = threadIdx.x;
    const int lane = tid & 63, w = tid >> 6;
    const int lr = lane & 15, kg = lane >> 4;
    const int wr = w >> 2, wc = w & 3;

    // T1: XCD-aware swizzle (grids here are multiples of 8)
    const int nwg = gridDim.x;
    const int cpx = nwg >> 3;
    const int bid = (blockIdx.x & 7) * cpx + (blockIdx.x >> 3);
    int khalf = 0, tile = bid;
    if (SPLITK) { khalf = bid >> 7; tile = bid & 127; }
    const int nbx = N >> 8;
    const int bx = tile % nbx, by = tile / nbx;
    const int bm0 = by << 8, bn0 = bx << 8;
    if (SPLITK) { A += (size_t)khalf * K; Bt += (size_t)khalf * K; }

    const int NT = K >> 6;

    // half h: 0=A-lo 1=A-hi 2=B-lo 3=B-hi -> buf t&1
    auto stage = [&](int t, int h) {
        const int c = t & 1;
        const ushort_t* gb; int ld; char* sbase;
        if (h < 2) { gb = A + (size_t)bm0 * lda; ld = lda; sbase = (char*)sA; }
        else       { gb = Bt + (size_t)bn0 * ldb; ld = ldb; sbase = (char*)sB; }
        const int half = h & 1;
        #pragma unroll
        for (int j = 0; j < 2; ++j) {
            const int o = j * 8192 + tid * 16;       // byte within 16KB half
            const int row = half * 128 + (o >> 7);   // tile row
            const int slot = (o >> 4) & 7;
            gload_lds16(gb + (size_t)row * ld + t * 64 + ((slot ^ (row & 7)) << 3),
                        sbase + c * 32768 + half * 16384 + j * 8192 + w * 1024);
        }
    };
    auto lda_frag = [&](int c, int mi, int s) {
        const int row = mi * 32 + wr * 16 + lr;
        return *(const bf16x8*)((const char*)sA + c * 32768 + row * 128 +
                                (((s * 4 + kg) ^ (row & 7)) << 4));
    };
    auto ldb_frag = [&](int c, int ni, int s) {
        const int row = ni * 64 + wc * 16 + lr;
        return *(const bf16x8*)((const char*)sB + c * 32768 + row * 128 +
                                (((s * 4 + kg) ^ (row & 7)) << 4));
    };

    f32x4 acc[8][4];
    #pragma unroll
    for (int i = 0; i < 8; ++i)
        #pragma unroll
        for (int j = 0; j < 4; ++j)
            acc[i][j] = (f32x4){0.f, 0.f, 0.f, 0.f};

    // prologue: 7 halves in flight, confirm tile 0 (vmcnt 6 = 3 halves out)
    stage(0, 0); stage(0, 2); stage(0, 3); stage(0, 1);
    stage(1, 0); stage(1, 2); stage(1, 3);
    asm volatile("s_waitcnt vmcnt(6)" ::: "memory");
    BAR();

    for (int t = 0; t < NT; ++t) {
        const int c = t & 1;
        bf16x8 a[4][2], b[4][2];

        // ---- P1: quad (0,0): A-lo x B-lo ----
        #pragma unroll
        for (int mi = 0; mi < 4; ++mi)
            #pragma unroll
            for (int s = 0; s < 2; ++s) a[mi][s] = lda_frag(c, mi, s);
        #pragma unroll
        for (int ni = 0; ni < 2; ++ni)
            #pragma unroll
            for (int s = 0; s < 2; ++s) b[ni][s] = ldb_frag(c, ni, s);
        if (t + 1 < NT) stage(t + 1, 1);
        BAR();
        LGKM0();
        __builtin_amdgcn_s_setprio(1);
        #pragma unroll
        for (int mi = 0; mi < 4; ++mi)
            #pragma unroll
            for (int ni = 0; ni < 2; ++ni)
                #pragma unroll
                for (int s = 0; s < 2; ++s)
                    acc[mi][ni] = __builtin_amdgcn_mfma_f32_16x16x32_bf16(
                        a[mi][s], b[ni][s], acc[mi][ni], 0, 0, 0);
        __builtin_amdgcn_s_setprio(0);
        BAR();

        // ---- P2: quad (0,1): A-lo x B-hi ----
        #pragma unroll
        for (int ni = 2; ni < 4; ++ni)
            #pragma unroll
            for (int s = 0; s < 2; ++s) b[ni][s] = ldb_frag(c, ni, s);
        if (t + 2 < NT) stage(t + 2, 0);
        BAR();
        LGKM0();
        __builtin_amdgcn_s_setprio(1);
        #pragma unroll
        for (int mi = 0; mi < 4; ++mi)
            #pragma unroll
            for (int ni = 2; ni < 4; ++ni)
                #pragma unroll
                for (int s = 0; s < 2; ++s)
                    acc[mi][ni] = __builtin_amdgcn_mfma_f32_16x16x32_bf16(
                        a[mi][s], b[ni][s], acc[mi][ni], 0, 0, 0);
        __builtin_amdgcn_s_setprio(0);
        BAR();

        // ---- P3: quad (1,1): A-hi x B-hi ----
        #pragma unroll
        for (int mi = 0; mi < 4; ++mi)
            #pragma unroll
            for (int s = 0; s < 2; ++s) a[mi][s] = lda_frag(c, mi + 4, s);
        if (t + 2 < NT) stage(t + 2, 2);
        BAR();
        LGKM0();
        __builtin_amdgcn_s_setprio(1);
        #pragma unroll
        for (int mi = 0; mi < 4; ++mi)
            #pragma unroll
            for (int ni = 2; ni < 4; ++ni)
                #pragma unroll
                for (int s = 0; s < 2; ++s)
                    acc[mi + 4][ni] = __builtin_amdgcn_mfma_f32_16x16x32_bf16(
                        a[mi][s], b[ni][s], acc[mi + 4][ni], 0, 0, 0);
        __builtin_amdgcn_s_setprio(0);
        BAR();

        // ---- P4: quad (1,0): A-hi x B-lo ----
        if (t + 2 < NT) {
            stage(t + 2, 3);
            asm volatile("s_waitcnt vmcnt(6)" ::: "memory");
        } else {
            asm volatile("s_waitcnt vmcnt(0)" ::: "memory");
        }
        BAR();
        __builtin_amdgcn_s_setprio(1);
        #pragma unroll
        for (int mi = 0; mi < 4; ++mi)
            #pragma unroll
            for (int ni = 0; ni < 2; ++ni)
                #pragma unroll
                for (int s = 0; s < 2; ++s)
                    acc[mi + 4][ni] = __builtin_amdgcn_mfma_f32_16x16x32_bf16(
                        a[mi][s], b[ni][s], acc[mi + 4][ni], 0, 0, 0);
        __builtin_amdgcn_s_setprio(0);
        BAR();
    }

    // ---- epilogue ----
    #pragma unroll
    for (int mi = 0; mi < 8; ++mi) {
        #pragma unroll
        for (int ni = 0; ni < 4; ++ni) {
            const int n = bn0 + ni * 64 + wc * 16 + lr;
            const float bs = (n < 4096) ? bias0[n]
                           : (n < 5120) ? bias1[n - 4096] : bias2[n - 5120];
            const int mr = bm0 + mi * 32 + wr * 16 + kg * 4;
            #pragma unroll
            for (int r = 0; r < 4; ++r) {
                if (SPLITK) {
                    const int row = mr + r;
                    if (khalf == 0) {
                        Cf[(size_t)row * N + n] = acc[mi][ni][r] + bs;
                    } else {
                        float* P = (row < 1024) ? P0 : P1;
                        P[((size_t)(row & 1023) << 12) + n] = acc[mi][ni][r];
                    }
                } else {
                    const float val = acc[mi][ni][r] + bs;
                    if (OUT_BF16) Cb[(size_t)(mr + r) * N + n] = f2bf(val);
                    else          Cf[(size_t)(mr + r) * N + n] = val;
                }
            }
        }
    }
}

// ---------------- split-K reduce: out += partial ----------------
__global__ void reduce_add(const float* __restrict__ P0, const float* __restrict__ P1,
                           float* __restrict__ out)
{
    const int i4 = blockIdx.x * blockDim.x + threadIdx.x;
    if (i4 >= M_ * D_ / 4) return;
    const float4 p = (i4 < (1 << 20))
        ? *(const float4*)&P0[(size_t)i4 * 4]
        : *(const float4*)&P1[(size_t)(i4 - (1 << 20)) * 4];
    float4 o = *(float4*)&out[(size_t)i4 * 4];
    o.x += p.x; o.y += p.y; o.z += p.z; o.w += p.w;
    *(float4*)&out[(size_t)i4 * 4] = o;
}

// ---------------- RoPE in place (stride QN_), buf pre-offset to col start ----
__global__ void rope_bf16(ushort_t* __restrict__ buf, int nh, float scale)
{
    const int i = blockIdx.x * blockDim.x + threadIdx.x;
    const int total = B_ * S_ * nh * 64;
    if (i >= total) return;
    const int j     = i & 63;
    const int t2    = i >> 6;
    const int head  = t2 % nh;
    const int token = t2 / nh;
    const int s     = token % S_;
    const size_t base = (size_t)token * QN_ + head * HD_;
    const float inv = __expf(-9.210340371976184f * (2.f * j) / (float)HD_);
    const float ang = (float)s * inv;
    float sn, cs;
    __sincosf(ang, &sn, &cs);
    const float x1 = bf2f(buf[base + j]);
    const float x2 = bf2f(buf[base + j + 64]);
    buf[base + j]      = f2bf((x1 * cs - x2 * sn) * scale);
    buf[base + j + 64] = f2bf((x2 * cs + x1 * sn) * scale);
}

// ---------------- V transpose: qkv v-cols -> [B*G][HD][S] ----------------
__global__ __launch_bounds__(256) void vtrans(
    const ushort_t* __restrict__ vb,   // qkv + 5120
    ushort_t* __restrict__ vT)
{
    __shared__ ushort_t t[32][40];
    const int s0 = blockIdx.x * 32;
    const int d0 = blockIdx.y * 32;
    const int bg = blockIdx.z;
    const int b = bg >> 3, g = bg & 7;
    const int tid = threadIdx.x;
    const int row = tid >> 3, c4 = (tid & 7) * 4;
    const us4 v = *(const us4*)&vb[(size_t)(b * S_ + s0 + row) * QN_ + g * HD_ + d0 + c4];
    t[row][c4 + 0] = v.x; t[row][c4 + 1] = v.y;
    t[row][c4 + 2] = v.z; t[row][c4 + 3] = v.w;
    __syncthreads();
    us4 o;
    o.x = t[c4 + 0][row]; o.y = t[c4 + 1][row];
    o.z = t[c4 + 2][row]; o.w = t[c4 + 3][row];
    *(us4*)&vT[(size_t)(bg * HD_ + d0 + row) * S_ + s0 + c4] = o;
}

// ---------------- MFMA attention: block = (b, h, 64 q-rows), 4 waves ----------------
__global__ __launch_bounds__(256) void attn_mfma(
    const ushort_t* __restrict__ kb,   // qkv + 4096 (rope'd K cols)
    const ushort_t* __restrict__ vT,   // [B*G][HD][S]
    ushort_t* __restrict__ qb)         // qkv (rope'd+scaled q cols), in/out
{
    __shared__ ushort_t sKV[8192];          // 16 KB staging
    __shared__ ushort_t sP[4 * 16 * 512];   // 64 KB per-wave P

    const int q0 = blockIdx.x * 64;
    const int h = blockIdx.y, b = blockIdx.z;
    const int g = h >> 2;
    const int tid = threadIdx.x;
    const int lane = tid & 63, w = tid >> 6;
    const int lr = lane & 15, kg = lane >> 4;

    bf16x8 af[4];
    {
        const ushort_t* qrow = qb + (size_t)(b * S_ + q0 + w * 16 + lr) * QN_ + h * HD_;
        #pragma unroll
        for (int c = 0; c < 4; ++c)
            af[c] = *(const bf16x8*)(qrow + c * 32 + kg * 8);
    }

    f32x4 l[8][4];
    #pragma unroll
    for (int ch = 0; ch < 8; ++ch)
        #pragma unroll
        for (int t = 0; t < 4; ++t)
            l[ch][t] = (f32x4){0.f, 0.f, 0.f, 0.f};

    // ---- QK^T ----
    const ushort_t* kbase = kb + (size_t)b * S_ * QN_ + g * HD_;
    #pragma unroll
    for (int ch = 0; ch < 8; ++ch) {
        __syncthreads();
        #pragma unroll
        for (int i = 0; i < 4; ++i) {
            const int o = w * 4096 + i * 1024;
            const int key = (o >> 8) + (lane >> 4);
            const int sl = lane & 15;
            gload_lds16(kbase + (size_t)(ch * 64 + key) * QN_ + ((sl ^ (key & 15)) * 8),
                        (char*)sKV + o);
        }
        __syncthreads();
        #pragma unroll
        for (int t = 0; t < 4; ++t) {
            const int key = t * 16 + lr;
            #pragma unroll
            for (int c = 0; c < 4; ++c) {
                const bf16x8 bf = *(const bf16x8*)((const char*)sKV + key * 256 +
                                                   (((c * 4 + kg) ^ (key & 15)) << 4));
                l[ch][t] = __builtin_amdgcn_mfma_f32_16x16x32_bf16(af[c], bf, l[ch][t], 0, 0, 0);
            }
        }
    }

    // ---- softmax ----
    float inv[4];
    #pragma unroll
    for (int r = 0; r < 4; ++r) {
        float m = -1e30f;
        #pragma unroll
        for (int ch = 0; ch < 8; ++ch)
            #pragma unroll
            for (int t = 0; t < 4; ++t)
                m = fmaxf(m, l[ch][t][r]);
        #pragma unroll
        for (int msk = 1; msk <= 8; msk <<= 1)
            m = fmaxf(m, __shfl_xor(m, msk));
        float s = 0.f;
        const int q = kg * 4 + r;
        #pragma unroll
        for (int ch = 0; ch < 8; ++ch)
            #pragma unroll
            for (int t = 0; t < 4; ++t) {
                const float p = __expf(l[ch][t][r] - m);
                s += p;
                const int gs = ch * 8 + t * 2 + (lr >> 3);
                sP[w * 8192 + q * 512 + ((gs ^ q) << 3) + (lr & 7)] = f2bf(p);
            }
        #pragma unroll
        for (int msk = 1; msk <= 8; msk <<= 1)
            s += __shfl_xor(s, msk);
        inv[r] = 1.f / s;
    }

    // ---- PV ----
    f32x4 oacc[8];
    #pragma unroll
    for (int dt = 0; dt < 8; ++dt) oacc[dt] = (f32x4){0.f, 0.f, 0.f, 0.f};

    const ushort_t* vbase = vT + (size_t)(b * G_ + g) * HD_ * S_;
    for (int ch = 0; ch < 8; ++ch) {
        __syncthreads();
        #pragma unroll
        for (int i = 0; i < 4; ++i) {
            const int o = w * 4096 + i * 1024;
            const int d = (o >> 7) + (lane >> 3);
            const int sl = lane & 7;
            gload_lds16(vbase + (size_t)d * S_ + ch * 64 + ((sl ^ (d & 7)) * 8),
                        (char*)sKV + o);
        }
        __syncthreads();
        #pragma unroll
        for (int c2 = 0; c2 < 2; ++c2) {
            const int gs = ch * 8 + c2 * 4 + kg;
            const bf16x8 ap = *(const bf16x8*)((const char*)sP + w * 16384 + lr * 1024 +
                                               ((gs ^ lr) << 4));
            #pragma unroll
            for (int dt = 0; dt < 8; ++dt) {
                const int d = dt * 16 + lr;
                const bf16x8 bv = *(const bf16x8*)((const char*)sKV + d * 128 +
                                                   (((c2 * 4 + kg) ^ (d & 7)) << 4));
                oacc[dt] = __builtin_amdgcn_mfma_f32_16x16x32_bf16(ap, bv, oacc[dt], 0, 0, 0);
            }
        }
    }

    #pragma unroll
    for (int dt = 0; dt < 8; ++dt) {
        #pragma unroll
        for (int r = 0; r < 4; ++r) {
            const int q = kg * 4 + r;
            qb[(size_t)(b * S_ + q0 + w * 16 + q) * QN_ + h * HD_ + dt * 16 + lr] =
                f2bf(oacc[dt][r] * inv[r]);
        }
    }
}

extern "C" void kernel_launch(void* const* d_in, const int* in_sizes, int n_in,
                              void* d_out, int out_size, void* d_ws, size_t ws_size,
                              hipStream_t stream)
{
    const float* x  = (const float*)d_in[0];
    const float* wq = (const float*)d_in[1];
    const float* bq = (const float*)d_in[2];
    const float* wk = (const float*)d_in[3];
    const float* bk = (const float*)d_in[4];
    const float* wv = (const float*)d_in[5];
    const float* bv = (const float*)d_in[6];
    const float* wo = (const float*)d_in[7];
    const float* bo = (const float*)d_in[8];
    float* out = (float*)d_out;

    char* ws = (char*)d_ws;
    ushort_t* xb   = (ushort_t*)(ws);                 // 16 MB: x bf16 [2048][4096]; later splitK P0
    ushort_t* Wt   = (ushort_t*)(ws + (16u << 20));   // 48 MB: [6144][4096] wq|wk|wv; later wo rows 0-4095
    ushort_t* vT   = (ushort_t*)(ws + (48u << 20));   //  4 MB: dead wk rows after QKV GEMM
    ushort_t* qkv  = (ushort_t*)(ws + (64u << 20));   // 24 MB: [2048][6144] bf16
    float* p0      = (float*)xb;                      // 16 MB fp32 [1024][4096] (xb dead post-QKV)
    float* p1      = (float*)(ws + (48u << 20));      // 16 MB fp32 (vT + dead wk/wv rows, post-attn)
    // total 88 MB

    // weights first, x last -> QKV GEMM inputs are the freshest L3 stream
    wconv<<<dim3(D_ / 32, D_ / 32), 256, 0, stream>>>(wq, Wt, D_, D_);
    wconv<<<dim3(KV_ / 32, D_ / 32), 256, 0, stream>>>(wk, Wt + (size_t)4096 * 4096, D_, KV_);
    wconv<<<dim3(KV_ / 32, D_ / 32), 256, 0, stream>>>(wv, Wt + (size_t)5120 * 4096, D_, KV_);
    xconv<<<(M_ * D_ / 8 + 255) / 256, 256, 0, stream>>>(x, xb, M_ * D_ / 8);

    // fused QKV projection: [2048][6144]
    gemm8<1, 0><<<(QN_ / 256) * (M_ / 256), 512, 0, stream>>>(
        xb, D_, Wt, D_, bq, bk, bv, nullptr, qkv, nullptr, nullptr, M_, QN_, D_);

    vtrans<<<dim3(S_ / 32, HD_ / 32, B_ * G_), 256, 0, stream>>>(qkv + 5120, vT);

    rope_bf16<<<(B_ * S_ * H_ * 64 + 255) / 256, 256, 0, stream>>>(qkv, H_, 1.f / 128.f);
    rope_bf16<<<(B_ * S_ * G_ * 64 + 255) / 256, 256, 0, stream>>>(qkv + 4096, G_, 1.f);

    attn_mfma<<<dim3(S_ / 64, H_, B_), 256, 0, stream>>>(qkv + 4096, vT, qkv);

    // wo -> rows 0-4095 of Wt (wq part is dead now)
    wconv<<<dim3(D_ / 32, D_ / 32), 256, 0, stream>>>(wo, Wt, D_, D_);

    // O projection, split-K=2 across a full 256-block grid
    gemm8<0, 1><<<256, 512, 0, stream>>>(
        qkv, QN_, Wt, D_, bo, bo, bo, out, nullptr, p0, p1, M_, D_, 2048);
    reduce_add<<<(M_ * D_ / 4 + 255) / 256, 256, 0, stream>>>(p0, p1, out);
}

// Round 8
// 311.328 us; speedup vs baseline: 15.0736x; 1.0504x over previous
//
#include <hip/hip_runtime.h>
#include <math.h>

typedef unsigned short ushort_t;
typedef __attribute__((ext_vector_type(8))) short bf16x8;
typedef __attribute__((ext_vector_type(4))) float f32x4;
typedef __attribute__((ext_vector_type(4))) unsigned short us4;
typedef __attribute__((ext_vector_type(8))) unsigned short us8;

#define B_   4
#define S_   512
#define D_   4096
#define H_   32
#define G_   8
#define HD_  128
#define KV_  1024
#define M_   (B_ * S_)   // 2048
#define QN_  6144        // fused QKV column count

__device__ __forceinline__ float bf2f(ushort_t u) {
    union { unsigned u; float f; } x; x.u = ((unsigned)u) << 16; return x.f;
}
__device__ __forceinline__ ushort_t f2bf(float f) {
    union { float f; unsigned u; } x; x.f = f;
    unsigned r = x.u + 0x7fffu + ((x.u >> 16) & 1u);   // round-to-nearest-even
    return (ushort_t)(r >> 16);
}

typedef const __attribute__((address_space(1))) void* gptr_t;
typedef __attribute__((address_space(3))) void* ldsptr_t;

__device__ __forceinline__ void gload_lds16(const void* g, void* lds) {
    __builtin_amdgcn_global_load_lds((gptr_t)g, (ldsptr_t)lds, 16, 0, 0);
}

#define BAR() asm volatile("s_barrier" ::: "memory")
#define LGKM0() do { asm volatile("s_waitcnt lgkmcnt(0)" ::: "memory"); \
                     __builtin_amdgcn_sched_barrier(0); } while (0)

// ---------------- fp32 -> bf16 elementwise ----------------
__global__ void xconv(const float* __restrict__ x, ushort_t* __restrict__ xb, int n8)
{
    const int i = blockIdx.x * blockDim.x + threadIdx.x;
    if (i >= n8) return;
    const float4 a = *(const float4*)&x[(size_t)i * 8];
    const float4 b = *(const float4*)&x[(size_t)i * 8 + 4];
    us8 o;
    o[0] = f2bf(a.x); o[1] = f2bf(a.y); o[2] = f2bf(a.z); o[3] = f2bf(a.w);
    o[4] = f2bf(b.x); o[5] = f2bf(b.y); o[6] = f2bf(b.z); o[7] = f2bf(b.w);
    *(us8*)&xb[(size_t)i * 8] = o;
}

// ------- fused W transpose: {wq|wk|wv} [4096][N] fp32 -> Wt [6144][4096] bf16 -------
__global__ __launch_bounds__(256) void wconv_all(
    const float* __restrict__ wq, const float* __restrict__ wk,
    const float* __restrict__ wv, ushort_t* __restrict__ Wt)
{
    __shared__ float t[32][33];
    const int n0 = blockIdx.x * 32, k0 = blockIdx.y * 32;
    const float* W; int nsrc, N;
    if (n0 < 4096)      { W = wq; nsrc = n0;        N = 4096; }
    else if (n0 < 5120) { W = wk; nsrc = n0 - 4096; N = 1024; }
    else                { W = wv; nsrc = n0 - 5120; N = 1024; }
    const int tid = threadIdx.x;
    const int r = tid >> 3, c4 = (tid & 7) * 4;
    const float4 v = *(const float4*)&W[(size_t)(k0 + r) * N + nsrc + c4];
    t[r][c4 + 0] = v.x; t[r][c4 + 1] = v.y; t[r][c4 + 2] = v.z; t[r][c4 + 3] = v.w;
    __syncthreads();
    us4 o;
    o.x = f2bf(t[c4 + 0][r]);
    o.y = f2bf(t[c4 + 1][r]);
    o.z = f2bf(t[c4 + 2][r]);
    o.w = f2bf(t[c4 + 3][r]);
    *(us4*)&Wt[(size_t)(n0 + r) * D_ + k0 + c4] = o;
}

// ---------------- W [K][N] fp32 -> Wt [N][K] bf16 (single, for wo) ----------------
__global__ __launch_bounds__(256) void wconv(
    const float* __restrict__ W, ushort_t* __restrict__ Wt, int K, int N)
{
    __shared__ float t[32][33];
    const int n0 = blockIdx.x * 32, k0 = blockIdx.y * 32;
    const int tid = threadIdx.x;
    const int r = tid >> 3, c4 = (tid & 7) * 4;
    const float4 v = *(const float4*)&W[(size_t)(k0 + r) * N + n0 + c4];
    t[r][c4 + 0] = v.x; t[r][c4 + 1] = v.y; t[r][c4 + 2] = v.z; t[r][c4 + 3] = v.w;
    __syncthreads();
    us4 o;
    o.x = f2bf(t[c4 + 0][r]);
    o.y = f2bf(t[c4 + 1][r]);
    o.z = f2bf(t[c4 + 2][r]);
    o.w = f2bf(t[c4 + 3][r]);
    *(us4*)&Wt[(size_t)(n0 + r) * K + k0 + c4] = o;
}

// ============ 256x256 8-phase MFMA GEMM (T1+T2+T3+T4+T5) ============
// C[M,N] = A[M,K] @ Bt[N,K]^T + bias.  BK=64, 8 waves (2M x 4N),
// per-wave C = 128x64 (8x4 frags of 16x16), 64 MFMA per K-tile per wave.
// Fragment row maps align with staging halves:
//   A frag row = mi*32 + wr*16 + lr  -> mi 0-3 == A-lo (P1), mi 4-7 == A-hi (P3)
//   B frag row = ni*64 + wc*16 + lr  -> ni 0-1 == B-lo (P1), ni 2-3 == B-hi (P2)
// SPLITK: swizzled bid>>7 selects K-half; khalf0 -> Cf+bias, khalf1 -> raw P0/P1.
// ROPE (QKV only): rotate-half partner of col n is n^64 == acc[mi][ni^1];
// jj = n&63 = wc*16+lr is lane-constant. q cols get *1/128 (two HD^-0.5).
template<int OUT_BF16, int SPLITK, int ROPE>
__global__ __launch_bounds__(512, 2) void gemm8(
    const ushort_t* __restrict__ A, int lda,
    const ushort_t* __restrict__ Bt, int ldb,
    const float* __restrict__ bias0, const float* __restrict__ bias1,
    const float* __restrict__ bias2,
    float* __restrict__ Cf, ushort_t* __restrict__ Cb,
    float* __restrict__ P0, float* __restrict__ P1,
    int M, int N, int K)
{
    __shared__ ushort_t sA[2][256 * 64];   // 64 KiB
    __shared__ ushort_t sB[2][256 * 64];   // 64 KiB

    const int tid = threadIdx.x;
    const int lane = tid & 63, w = tid >> 6;
    const int lr = lane & 15, kg = lane >> 4;
    const int wr = w >> 2, wc = w & 3;

    // T1: XCD-aware swizzle (grids here are multiples of 8)
    const int nwg = gridDim.x;
    const int cpx = nwg >> 3;
    const int bid = (blockIdx.x & 7) * cpx + (blockIdx.x >> 3);
    int khalf = 0, tile = bid;
    if (SPLITK) { khalf = bid >> 7; tile = bid & 127; }
    const int nbx = N >> 8;
    const int bx = tile % nbx, by = tile / nbx;
    const int bm0 = by << 8, bn0 = bx << 8;
    if (SPLITK) { A += (size_t)khalf * K; Bt += (size_t)khalf * K; }

    const int NT = K >> 6;

    // half h: 0=A-lo 1=A-hi 2=B-lo 3=B-hi -> buf t&1
    auto stage = [&](int t, int h) {
        const int c = t & 1;
        const ushort_t* gb; int ld; char* sbase;
        if (h < 2) { gb = A + (size_t)bm0 * lda; ld = lda; sbase = (char*)sA; }
        else       { gb = Bt + (size_t)bn0 * ldb; ld = ldb; sbase = (char*)sB; }
        const int half = h & 1;
        #pragma unroll
        for (int j = 0; j < 2; ++j) {
            const int o = j * 8192 + tid * 16;       // byte within 16KB half
            const int row = half * 128 + (o >> 7);   // tile row
            const int slot = (o >> 4) & 7;
            gload_lds16(gb + (size_t)row * ld + t * 64 + ((slot ^ (row & 7)) << 3),
                        sbase + c * 32768 + half * 16384 + j * 8192 + w * 1024);
        }
    };
    auto lda_frag = [&](int c, int mi, int s) {
        const int row = mi * 32 + wr * 16 + lr;
        return *(const bf16x8*)((const char*)sA + c * 32768 + row * 128 +
                                (((s * 4 + kg) ^ (row & 7)) << 4));
    };
    auto ldb_frag = [&](int c, int ni, int s) {
        const int row = ni * 64 + wc * 16 + lr;
        return *(const bf16x8*)((const char*)sB + c * 32768 + row * 128 +
                                (((s * 4 + kg) ^ (row & 7)) << 4));
    };

    f32x4 acc[8][4];
    #pragma unroll
    for (int i = 0; i < 8; ++i)
        #pragma unroll
        for (int j = 0; j < 4; ++j)
            acc[i][j] = (f32x4){0.f, 0.f, 0.f, 0.f};

    // prologue: 7 halves in flight, confirm tile 0 (vmcnt 6 = 3 halves out)
    stage(0, 0); stage(0, 2); stage(0, 3); stage(0, 1);
    stage(1, 0); stage(1, 2); stage(1, 3);
    asm volatile("s_waitcnt vmcnt(6)" ::: "memory");
    BAR();

    for (int t = 0; t < NT; ++t) {
        const int c = t & 1;
        bf16x8 a[4][2], b[4][2];

        // ---- P1: quad (0,0): A-lo x B-lo ----
        #pragma unroll
        for (int mi = 0; mi < 4; ++mi)
            #pragma unroll
            for (int s = 0; s < 2; ++s) a[mi][s] = lda_frag(c, mi, s);
        #pragma unroll
        for (int ni = 0; ni < 2; ++ni)
            #pragma unroll
            for (int s = 0; s < 2; ++s) b[ni][s] = ldb_frag(c, ni, s);
        if (t + 1 < NT) stage(t + 1, 1);
        BAR();
        LGKM0();
        __builtin_amdgcn_s_setprio(1);
        #pragma unroll
        for (int mi = 0; mi < 4; ++mi)
            #pragma unroll
            for (int ni = 0; ni < 2; ++ni)
                #pragma unroll
                for (int s = 0; s < 2; ++s)
                    acc[mi][ni] = __builtin_amdgcn_mfma_f32_16x16x32_bf16(
                        a[mi][s], b[ni][s], acc[mi][ni], 0, 0, 0);
        __builtin_amdgcn_s_setprio(0);
        BAR();

        // ---- P2: quad (0,1): A-lo x B-hi ----
        #pragma unroll
        for (int ni = 2; ni < 4; ++ni)
            #pragma unroll
            for (int s = 0; s < 2; ++s) b[ni][s] = ldb_frag(c, ni, s);
        if (t + 2 < NT) stage(t + 2, 0);
        BAR();
        LGKM0();
        __builtin_amdgcn_s_setprio(1);
        #pragma unroll
        for (int mi = 0; mi < 4; ++mi)
            #pragma unroll
            for (int ni = 2; ni < 4; ++ni)
                #pragma unroll
                for (int s = 0; s < 2; ++s)
                    acc[mi][ni] = __builtin_amdgcn_mfma_f32_16x16x32_bf16(
                        a[mi][s], b[ni][s], acc[mi][ni], 0, 0, 0);
        __builtin_amdgcn_s_setprio(0);
        BAR();

        // ---- P3: quad (1,1): A-hi x B-hi ----
        #pragma unroll
        for (int mi = 0; mi < 4; ++mi)
            #pragma unroll
            for (int s = 0; s < 2; ++s) a[mi][s] = lda_frag(c, mi + 4, s);
        if (t + 2 < NT) stage(t + 2, 2);
        BAR();
        LGKM0();
        __builtin_amdgcn_s_setprio(1);
        #pragma unroll
        for (int mi = 0; mi < 4; ++mi)
            #pragma unroll
            for (int ni = 2; ni < 4; ++ni)
                #pragma unroll
                for (int s = 0; s < 2; ++s)
                    acc[mi + 4][ni] = __builtin_amdgcn_mfma_f32_16x16x32_bf16(
                        a[mi][s], b[ni][s], acc[mi + 4][ni], 0, 0, 0);
        __builtin_amdgcn_s_setprio(0);
        BAR();

        // ---- P4: quad (1,0): A-hi x B-lo ----
        if (t + 2 < NT) {
            stage(t + 2, 3);
            asm volatile("s_waitcnt vmcnt(6)" ::: "memory");
        } else {
            asm volatile("s_waitcnt vmcnt(0)" ::: "memory");
        }
        BAR();
        __builtin_amdgcn_s_setprio(1);
        #pragma unroll
        for (int mi = 0; mi < 4; ++mi)
            #pragma unroll
            for (int ni = 0; ni < 2; ++ni)
                #pragma unroll
                for (int s = 0; s < 2; ++s)
                    acc[mi + 4][ni] = __builtin_amdgcn_mfma_f32_16x16x32_bf16(
                        a[mi][s], b[ni][s], acc[mi + 4][ni], 0, 0, 0);
        __builtin_amdgcn_s_setprio(0);
        BAR();
    }

    // ---- epilogue ----
    if (ROPE && bn0 < 5120) {
        // q cols (bn0<4096) and k cols (4096..5119): rope pairs (ni, ni^1)
        const float scale = (bn0 < 4096) ? (1.f / 128.f) : 1.f;
        const int jj = wc * 16 + lr;                                // n & 63
        const float invf = __expf(-0.1439115683121279f * (float)jj); // 10000^(-jj/64)
        #pragma unroll
        for (int mi = 0; mi < 8; ++mi) {
            const int mr = bm0 + mi * 32 + wr * 16 + kg * 4;
            #pragma unroll
            for (int r = 0; r < 4; ++r) {
                const int srow = (mr + r) & 511;
                float sn, cs;
                __sincosf((float)srow * invf, &sn, &cs);
                #pragma unroll
                for (int nip = 0; nip < 2; ++nip) {
                    const int n_lo = bn0 + nip * 128 + jj;          // ni = 2*nip
                    const int n_hi = n_lo + 64;                     // ni = 2*nip+1
                    const float b_lo = (n_lo < 4096) ? bias0[n_lo]
                                     : (n_lo < 5120) ? bias1[n_lo - 4096] : bias2[n_lo - 5120];
                    const float b_hi = (n_hi < 4096) ? bias0[n_hi]
                                     : (n_hi < 5120) ? bias1[n_hi - 4096] : bias2[n_hi - 5120];
                    const float a_lo = acc[mi][nip * 2][r] + b_lo;
                    const float a_hi = acc[mi][nip * 2 + 1][r] + b_hi;
                    Cb[(size_t)(mr + r) * N + n_lo] = f2bf((a_lo * cs - a_hi * sn) * scale);
                    Cb[(size_t)(mr + r) * N + n_hi] = f2bf((a_hi * cs + a_lo * sn) * scale);
                }
            }
        }
        return;
    }
    #pragma unroll
    for (int mi = 0; mi < 8; ++mi) {
        #pragma unroll
        for (int ni = 0; ni < 4; ++ni) {
            const int n = bn0 + ni * 64 + wc * 16 + lr;
            const float bs = (n < 4096) ? bias0[n]
                           : (n < 5120) ? bias1[n - 4096] : bias2[n - 5120];
            const int mr = bm0 + mi * 32 + wr * 16 + kg * 4;
            #pragma unroll
            for (int r = 0; r < 4; ++r) {
                if (SPLITK) {
                    const int row = mr + r;
                    if (khalf == 0) {
                        Cf[(size_t)row * N + n] = acc[mi][ni][r] + bs;
                    } else {
                        float* P = (row < 1024) ? P0 : P1;
                        P[((size_t)(row & 1023) << 12) + n] = acc[mi][ni][r];
                    }
                } else {
                    const float val = acc[mi][ni][r] + bs;
                    if (OUT_BF16) Cb[(size_t)(mr + r) * N + n] = f2bf(val);
                    else          Cf[(size_t)(mr + r) * N + n] = val;
                }
            }
        }
    }
}

// ---------------- split-K reduce: out += partial (grid-stride) ----------------
__global__ void reduce_add(const float* __restrict__ P0, const float* __restrict__ P1,
                           float* __restrict__ out)
{
    const int n4 = M_ * D_ / 4;
    for (int i4 = blockIdx.x * blockDim.x + threadIdx.x; i4 < n4;
         i4 += gridDim.x * blockDim.x) {
        const float4 p = (i4 < (1 << 20))
            ? *(const float4*)&P0[(size_t)i4 * 4]
            : *(const float4*)&P1[(size_t)(i4 - (1 << 20)) * 4];
        float4 o = *(float4*)&out[(size_t)i4 * 4];
        o.x += p.x; o.y += p.y; o.z += p.z; o.w += p.w;
        *(float4*)&out[(size_t)i4 * 4] = o;
    }
}

// ---------------- V transpose: qkv v-cols -> [B*G][HD][S] ----------------
__global__ __launch_bounds__(256) void vtrans(
    const ushort_t* __restrict__ vb,   // qkv + 5120
    ushort_t* __restrict__ vT)
{
    __shared__ ushort_t t[32][40];
    const int s0 = blockIdx.x * 32;
    const int d0 = blockIdx.y * 32;
    const int bg = blockIdx.z;
    const int b = bg >> 3, g = bg & 7;
    const int tid = threadIdx.x;
    const int row = tid >> 3, c4 = (tid & 7) * 4;
    const us4 v = *(const us4*)&vb[(size_t)(b * S_ + s0 + row) * QN_ + g * HD_ + d0 + c4];
    t[row][c4 + 0] = v.x; t[row][c4 + 1] = v.y;
    t[row][c4 + 2] = v.z; t[row][c4 + 3] = v.w;
    __syncthreads();
    us4 o;
    o.x = t[c4 + 0][row]; o.y = t[c4 + 1][row];
    o.z = t[c4 + 2][row]; o.w = t[c4 + 3][row];
    *(us4*)&vT[(size_t)(bg * HD_ + d0 + row) * S_ + s0 + c4] = o;
}

// ---------------- MFMA attention: block = (b, h, 64 q-rows), 4 waves ----------------
__global__ __launch_bounds__(256) void attn_mfma(
    const ushort_t* __restrict__ kb,   // qkv + 4096 (rope'd K cols)
    const ushort_t* __restrict__ vT,   // [B*G][HD][S]
    ushort_t* __restrict__ qb)         // qkv (rope'd+scaled q cols), in/out
{
    __shared__ ushort_t sKV[8192];          // 16 KB staging
    __shared__ ushort_t sP[4 * 16 * 512];   // 64 KB per-wave P

    const int q0 = blockIdx.x * 64;
    const int h = blockIdx.y, b = blockIdx.z;
    const int g = h >> 2;
    const int tid = threadIdx.x;
    const int lane = tid & 63, w = tid >> 6;
    const int lr = lane & 15, kg = lane >> 4;

    bf16x8 af[4];
    {
        const ushort_t* qrow = qb + (size_t)(b * S_ + q0 + w * 16 + lr) * QN_ + h * HD_;
        #pragma unroll
        for (int c = 0; c < 4; ++c)
            af[c] = *(const bf16x8*)(qrow + c * 32 + kg * 8);
    }

    f32x4 l[8][4];
    #pragma unroll
    for (int ch = 0; ch < 8; ++ch)
        #pragma unroll
        for (int t = 0; t < 4; ++t)
            l[ch][t] = (f32x4){0.f, 0.f, 0.f, 0.f};

    // ---- QK^T ----
    const ushort_t* kbase = kb + (size_t)b * S_ * QN_ + g * HD_;
    #pragma unroll
    for (int ch = 0; ch < 8; ++ch) {
        __syncthreads();
        #pragma unroll
        for (int i = 0; i < 4; ++i) {
            const int o = w * 4096 + i * 1024;
            const int key = (o >> 8) + (lane >> 4);
            const int sl = lane & 15;
            gload_lds16(kbase + (size_t)(ch * 64 + key) * QN_ + ((sl ^ (key & 15)) * 8),
                        (char*)sKV + o);
        }
        __syncthreads();
        #pragma unroll
        for (int t = 0; t < 4; ++t) {
            const int key = t * 16 + lr;
            #pragma unroll
            for (int c = 0; c < 4; ++c) {
                const bf16x8 bf = *(const bf16x8*)((const char*)sKV + key * 256 +
                                                   (((c * 4 + kg) ^ (key & 15)) << 4));
                l[ch][t] = __builtin_amdgcn_mfma_f32_16x16x32_bf16(af[c], bf, l[ch][t], 0, 0, 0);
            }
        }
    }

    // ---- softmax ----
    float inv[4];
    #pragma unroll
    for (int r = 0; r < 4; ++r) {
        float m = -1e30f;
        #pragma unroll
        for (int ch = 0; ch < 8; ++ch)
            #pragma unroll
            for (int t = 0; t < 4; ++t)
                m = fmaxf(m, l[ch][t][r]);
        #pragma unroll
        for (int msk = 1; msk <= 8; msk <<= 1)
            m = fmaxf(m, __shfl_xor(m, msk));
        float s = 0.f;
        const int q = kg * 4 + r;
        #pragma unroll
        for (int ch = 0; ch < 8; ++ch)
            #pragma unroll
            for (int t = 0; t < 4; ++t) {
                const float p = __expf(l[ch][t][r] - m);
                s += p;
                const int gs = ch * 8 + t * 2 + (lr >> 3);
                sP[w * 8192 + q * 512 + ((gs ^ q) << 3) + (lr & 7)] = f2bf(p);
            }
        #pragma unroll
        for (int msk = 1; msk <= 8; msk <<= 1)
            s += __shfl_xor(s, msk);
        inv[r] = 1.f / s;
    }

    // ---- PV ----
    f32x4 oacc[8];
    #pragma unroll
    for (int dt = 0; dt < 8; ++dt) oacc[dt] = (f32x4){0.f, 0.f, 0.f, 0.f};

    const ushort_t* vbase = vT + (size_t)(b * G_ + g) * HD_ * S_;
    for (int ch = 0; ch < 8; ++ch) {
        __syncthreads();
        #pragma unroll
        for (int i = 0; i < 4; ++i) {
            const int o = w * 4096 + i * 1024;
            const int d = (o >> 7) + (lane >> 3);
            const int sl = lane & 7;
            gload_lds16(vbase + (size_t)d * S_ + ch * 64 + ((sl ^ (d & 7)) * 8),
                        (char*)sKV + o);
        }
        __syncthreads();
        #pragma unroll
        for (int c2 = 0; c2 < 2; ++c2) {
            const int gs = ch * 8 + c2 * 4 + kg;
            const bf16x8 ap = *(const bf16x8*)((const char*)sP + w * 16384 + lr * 1024 +
                                               ((gs ^ lr) << 4));
            #pragma unroll
            for (int dt = 0; dt < 8; ++dt) {
                const int d = dt * 16 + lr;
                const bf16x8 bv = *(const bf16x8*)((const char*)sKV + d * 128 +
                                                   (((c2 * 4 + kg) ^ (d & 7)) << 4));
                oacc[dt] = __builtin_amdgcn_mfma_f32_16x16x32_bf16(ap, bv, oacc[dt], 0, 0, 0);
            }
        }
    }

    #pragma unroll
    for (int dt = 0; dt < 8; ++dt) {
        #pragma unroll
        for (int r = 0; r < 4; ++r) {
            const int q = kg * 4 + r;
            qb[(size_t)(b * S_ + q0 + w * 16 + q) * QN_ + h * HD_ + dt * 16 + lr] =
                f2bf(oacc[dt][r] * inv[r]);
        }
    }
}

extern "C" void kernel_launch(void* const* d_in, const int* in_sizes, int n_in,
                              void* d_out, int out_size, void* d_ws, size_t ws_size,
                              hipStream_t stream)
{
    const float* x  = (const float*)d_in[0];
    const float* wq = (const float*)d_in[1];
    const float* bq = (const float*)d_in[2];
    const float* wk = (const float*)d_in[3];
    const float* bk = (const float*)d_in[4];
    const float* wv = (const float*)d_in[5];
    const float* bv = (const float*)d_in[6];
    const float* wo = (const float*)d_in[7];
    const float* bo = (const float*)d_in[8];
    float* out = (float*)d_out;

    char* ws = (char*)d_ws;
    ushort_t* xb   = (ushort_t*)(ws);                 // 16 MB: x bf16 [2048][4096]; later splitK P0
    ushort_t* Wt   = (ushort_t*)(ws + (16u << 20));   // 48 MB: [6144][4096] wq|wk|wv; later wo rows 0-4095
    ushort_t* vT   = (ushort_t*)(ws + (48u << 20));   //  4 MB: dead wk rows after QKV GEMM
    ushort_t* qkv  = (ushort_t*)(ws + (64u << 20));   // 24 MB: [2048][6144] bf16
    float* p0      = (float*)xb;                      // 16 MB fp32 (xb dead post-QKV)
    float* p1      = (float*)(ws + (48u << 20));      // 16 MB fp32 (vT + dead rows, post-attn)
    // total 88 MB

    // weights first, x last -> QKV GEMM inputs are the freshest L3 stream
    wconv_all<<<dim3(QN_ / 32, D_ / 32), 256, 0, stream>>>(wq, wk, wv, Wt);
    xconv<<<(M_ * D_ / 8 + 255) / 256, 256, 0, stream>>>(x, xb, M_ * D_ / 8);

    // fused QKV projection + RoPE + q-scale in epilogue: [2048][6144]
    gemm8<1, 0, 1><<<(QN_ / 256) * (M_ / 256), 512, 0, stream>>>(
        xb, D_, Wt, D_, bq, bk, bv, nullptr, qkv, nullptr, nullptr, M_, QN_, D_);

    vtrans<<<dim3(S_ / 32, HD_ / 32, B_ * G_), 256, 0, stream>>>(qkv + 5120, vT);

    attn_mfma<<<dim3(S_ / 64, H_, B_), 256, 0, stream>>>(qkv + 4096, vT, qkv);

    // wo -> rows 0-4095 of Wt (wq part is dead now)
    wconv<<<dim3(D_ / 32, D_ / 32), 256, 0, stream>>>(wo, Wt, D_, D_);

    // O projection, split-K=2 across a full 256-block grid
    gemm8<0, 1, 0><<<256, 512, 0, stream>>>(
        qkv, QN_, Wt, D_, bo, bo, bo, out, nullptr, p0, p1, M_, D_, 2048);
    reduce_add<<<2048, 256, 0, stream>>>(p0, p1, out);
}